// Round 1
// baseline (3120.260 us; speedup 1.0000x reference)
//
#include <hip/hip_runtime.h>
#include <math.h>

#define HID 128

__device__ __forceinline__ float silu_f(float v) {
    return v / (1.0f + __expf(-v));
}
__device__ __forceinline__ float sigmoid_f(float v) {
    return 1.0f / (1.0f + __expf(-v));
}

__global__ void k_count(const int* __restrict__ rows, float* __restrict__ cnt, int E) {
    int i = blockIdx.x * 256 + threadIdx.x;
    if (i < E) atomicAdd(&cnt[rows[i]], 1.0f);
}

__global__ void k_embed(const float* __restrict__ hin, const float* __restrict__ w,
                        const float* __restrict__ b, float* __restrict__ hout, int N) {
    int idx = blockIdx.x * 256 + threadIdx.x;
    if (idx >= N * HID) return;
    int n = idx >> 7, j = idx & 127;
    float s = b[j];
    const float* hr = &hin[n * 6];
#pragma unroll
    for (int k = 0; k < 6; ++k) s += hr[k] * w[k * HID + j];
    hout[idx] = s;
}

// 64 edges per block, 256 threads. thread (ty,tx): edges ty*4..+3, hid dims tx*8..+7
__global__ __launch_bounds__(256, 2) void k_edge(
    const float* __restrict__ h, const float* __restrict__ x,
    const float* __restrict__ eattr,
    const int* __restrict__ rows, const int* __restrict__ cols,
    const float* __restrict__ ew1, const float* __restrict__ eb1,
    const float* __restrict__ ew2, const float* __restrict__ eb2,
    const float* __restrict__ aw, const float* __restrict__ ab,
    const float* __restrict__ cw1, const float* __restrict__ cb1,
    const float* __restrict__ cw2,
    float* __restrict__ aggh, float* __restrict__ aggx, int E)
{
    __shared__ __align__(16) float B[64][132];   // e_in chunks -> t1 -> m (reused)
    __shared__ float sCD[64][4];                 // coord diff xyz + radial
    __shared__ int sRow[64];
    __shared__ int sCol[64];

    const int t = threadIdx.x;
    const int tx = t & 15, ty = t >> 4;
    const int e0 = blockIdx.x * 64;

    if (t < 64) {
        int eg = e0 + t;
        int ec = eg < E ? eg : (E - 1);
        int r = rows[ec], c = cols[ec];
        sRow[t] = r; sCol[t] = c;
        float dx = x[r * 3 + 0] - x[c * 3 + 0];
        float dy = x[r * 3 + 1] - x[c * 3 + 1];
        float dz = x[r * 3 + 2] - x[c * 3 + 2];
        sCD[t][0] = dx; sCD[t][1] = dy; sCD[t][2] = dz;
        sCD[t][3] = dx * dx + dy * dy + dz * dz;
    }
    __syncthreads();

    float acc[4][8];
#pragma unroll
    for (int i = 0; i < 4; ++i)
#pragma unroll
        for (int j = 0; j < 8; ++j) acc[i][j] = 0.f;

    // ---- GEMM1: e_in[0:256] = [h[row] | h[col]], K in 8 chunks of 32 ----
    for (int kc = 0; kc < 8; ++kc) {
        const int kb = kc * 32;
        {
            int idx = t;
#pragma unroll
            for (int it = 0; it < 2; ++it, idx += 256) {
                int e = idx >> 3, c4 = idx & 7;
                int node = (kc < 4) ? sRow[e] : sCol[e];
                int koff = (kc < 4) ? kb : (kb - 128);
                float4 v = *(const float4*)&h[(size_t)node * HID + koff + c4 * 4];
                *(float4*)&B[e][c4 * 4] = v;
            }
        }
        __syncthreads();
        const float* wp = &ew1[(size_t)kb * HID + tx * 8];
#pragma unroll 4
        for (int kk = 0; kk < 32; ++kk) {
            float4 w0 = *(const float4*)&wp[kk * HID];
            float4 w1v = *(const float4*)&wp[kk * HID + 4];
            float wv[8] = {w0.x, w0.y, w0.z, w0.w, w1v.x, w1v.y, w1v.z, w1v.w};
            float av[4];
#pragma unroll
            for (int i = 0; i < 4; ++i) av[i] = B[ty * 4 + i][kk];
#pragma unroll
            for (int i = 0; i < 4; ++i)
#pragma unroll
                for (int j = 0; j < 8; ++j) acc[i][j] += av[i] * wv[j];
        }
        __syncthreads();
    }
    // ---- rank-3 tail: radial (k=256), edge_attr (k=257,258) ----
    {
        float wq[3][8];
        const float* w256 = &ew1[256 * HID + tx * 8];
        const float* w257 = &ew1[257 * HID + tx * 8];
        const float* w258 = &ew1[258 * HID + tx * 8];
#pragma unroll
        for (int j = 0; j < 8; ++j) { wq[0][j] = w256[j]; wq[1][j] = w257[j]; wq[2][j] = w258[j]; }
#pragma unroll
        for (int i = 0; i < 4; ++i) {
            int e = ty * 4 + i;
            int eg = e0 + e;
            int ec = eg < E ? eg : (E - 1);
            float rad = sCD[e][3];
            float a0 = eattr[(size_t)ec * 2 + 0];
            float a1 = eattr[(size_t)ec * 2 + 1];
#pragma unroll
            for (int j = 0; j < 8; ++j)
                acc[i][j] += rad * wq[0][j] + a0 * wq[1][j] + a1 * wq[2][j];
        }
    }
    // bias + silu -> t1 into B
    {
        float bb[8];
#pragma unroll
        for (int j = 0; j < 8; ++j) bb[j] = eb1[tx * 8 + j];
#pragma unroll
        for (int i = 0; i < 4; ++i)
#pragma unroll
            for (int j = 0; j < 8; ++j)
                B[ty * 4 + i][tx * 8 + j] = silu_f(acc[i][j] + bb[j]);
    }
    __syncthreads();

    // ---- GEMM2: t2 = silu(t1 @ ew2 + eb2), then attention gate ----
    float acc2[4][8];
#pragma unroll
    for (int i = 0; i < 4; ++i)
#pragma unroll
        for (int j = 0; j < 8; ++j) acc2[i][j] = 0.f;
    {
        const float* wp = &ew2[tx * 8];
#pragma unroll 4
        for (int k = 0; k < HID; ++k) {
            float4 w0 = *(const float4*)&wp[k * HID];
            float4 w1v = *(const float4*)&wp[k * HID + 4];
            float wv[8] = {w0.x, w0.y, w0.z, w0.w, w1v.x, w1v.y, w1v.z, w1v.w};
            float av[4];
#pragma unroll
            for (int i = 0; i < 4; ++i) av[i] = B[ty * 4 + i][k];
#pragma unroll
            for (int i = 0; i < 4; ++i)
#pragma unroll
                for (int j = 0; j < 8; ++j) acc2[i][j] += av[i] * wv[j];
        }
    }
    float t2v[4][8];
    {
        float bb[8], awv[8];
#pragma unroll
        for (int j = 0; j < 8; ++j) { bb[j] = eb2[tx * 8 + j]; awv[j] = aw[tx * 8 + j]; }
        float ab0 = ab[0];
#pragma unroll
        for (int i = 0; i < 4; ++i) {
            float p = 0.f;
#pragma unroll
            for (int j = 0; j < 8; ++j) {
                t2v[i][j] = silu_f(acc2[i][j] + bb[j]);
                p += t2v[i][j] * awv[j];
            }
            p += __shfl_xor(p, 1);
            p += __shfl_xor(p, 2);
            p += __shfl_xor(p, 4);
            p += __shfl_xor(p, 8);
            float att = sigmoid_f(p + ab0);
#pragma unroll
            for (int j = 0; j < 8; ++j) t2v[i][j] *= att;
        }
    }
    __syncthreads();   // all GEMM2 reads of B (t1) done
#pragma unroll
    for (int i = 0; i < 4; ++i)
#pragma unroll
        for (int j = 0; j < 8; ++j)
            B[ty * 4 + i][tx * 8 + j] = t2v[i][j];   // B now holds m
    __syncthreads();

    // ---- GEMM3: w = silu(m @ cw1 + cb1) @ cw2 ----
    float acc3[4][8];
#pragma unroll
    for (int i = 0; i < 4; ++i)
#pragma unroll
        for (int j = 0; j < 8; ++j) acc3[i][j] = 0.f;
    {
        const float* wp = &cw1[tx * 8];
#pragma unroll 4
        for (int k = 0; k < HID; ++k) {
            float4 w0 = *(const float4*)&wp[k * HID];
            float4 w1v = *(const float4*)&wp[k * HID + 4];
            float wv[8] = {w0.x, w0.y, w0.z, w0.w, w1v.x, w1v.y, w1v.z, w1v.w};
            float av[4];
#pragma unroll
            for (int i = 0; i < 4; ++i) av[i] = B[ty * 4 + i][k];
#pragma unroll
            for (int i = 0; i < 4; ++i)
#pragma unroll
                for (int j = 0; j < 8; ++j) acc3[i][j] += av[i] * wv[j];
        }
    }
    {
        float cbv[8], cw2v[8];
#pragma unroll
        for (int j = 0; j < 8; ++j) { cbv[j] = cb1[tx * 8 + j]; cw2v[j] = cw2[tx * 8 + j]; }
        float wc[4];
#pragma unroll
        for (int i = 0; i < 4; ++i) {
            float p = 0.f;
#pragma unroll
            for (int j = 0; j < 8; ++j) {
                float u = silu_f(acc3[i][j] + cbv[j]);
                p += u * cw2v[j];
            }
            p += __shfl_xor(p, 1);
            p += __shfl_xor(p, 2);
            p += __shfl_xor(p, 4);
            p += __shfl_xor(p, 8);
            wc[i] = p;
        }
        if (tx == 0) {
#pragma unroll
            for (int i = 0; i < 4; ++i) {
                int e = ty * 4 + i;
                int eg = e0 + e;
                if (eg < E) {
                    int r = sRow[e];
                    atomicAdd(&aggx[r * 3 + 0], sCD[e][0] * wc[i]);
                    atomicAdd(&aggx[r * 3 + 1], sCD[e][1] * wc[i]);
                    atomicAdd(&aggx[r * 3 + 2], sCD[e][2] * wc[i]);
                }
            }
        }
    }
    // ---- agg_h += m (m is in B) ----
    for (int idx = t; idx < 64 * HID; idx += 256) {
        int e = idx >> 7, c = idx & 127;
        if (e0 + e < E)
            atomicAdd(&aggh[(size_t)sRow[e] * HID + c], B[e][c]);
    }
}

// 64 nodes per block, 256 threads
__global__ __launch_bounds__(256, 2) void k_node(
    float* __restrict__ h, const float* __restrict__ aggh,
    const float* __restrict__ aggx, const float* __restrict__ cnt,
    float* __restrict__ x, float* __restrict__ vel,
    const float* __restrict__ vw1, const float* __restrict__ vb1,
    const float* __restrict__ vw2, const float* __restrict__ vb2,
    const float* __restrict__ nw1, const float* __restrict__ nb1,
    const float* __restrict__ nw2, const float* __restrict__ nb2,
    int N)
{
    __shared__ __align__(16) float BH[64][132];  // h, later t
    __shared__ __align__(16) float BG[64][132];  // agg_h
    const int t = threadIdx.x;
    const int tx = t & 15, ty = t >> 4;
    const int n0 = blockIdx.x * 64;

    for (int idx = t; idx < 64 * 32; idx += 256) {
        int r = idx >> 5, c4 = idx & 31;
        int n = n0 + r;
        float4 v0 = make_float4(0.f, 0.f, 0.f, 0.f), v1 = v0;
        if (n < N) {
            v0 = *(const float4*)&h[(size_t)n * HID + c4 * 4];
            v1 = *(const float4*)&aggh[(size_t)n * HID + c4 * 4];
        }
        *(float4*)&BH[r][c4 * 4] = v0;
        *(float4*)&BG[r][c4 * 4] = v1;
    }
    __syncthreads();

    // ---- phase A: vel scale = silu(h@vw1+vb1)@vw2 + vb2; update vel, x ----
    {
        float acc[4][8];
#pragma unroll
        for (int i = 0; i < 4; ++i)
#pragma unroll
            for (int j = 0; j < 8; ++j) acc[i][j] = 0.f;
        const float* wp = &vw1[tx * 8];
#pragma unroll 4
        for (int k = 0; k < HID; ++k) {
            float4 w0 = *(const float4*)&wp[k * HID];
            float4 w1v = *(const float4*)&wp[k * HID + 4];
            float wv[8] = {w0.x, w0.y, w0.z, w0.w, w1v.x, w1v.y, w1v.z, w1v.w};
            float av[4];
#pragma unroll
            for (int i = 0; i < 4; ++i) av[i] = BH[ty * 4 + i][k];
#pragma unroll
            for (int i = 0; i < 4; ++i)
#pragma unroll
                for (int j = 0; j < 8; ++j) acc[i][j] += av[i] * wv[j];
        }
        float bb[8], w2v[8];
#pragma unroll
        for (int j = 0; j < 8; ++j) { bb[j] = vb1[tx * 8 + j]; w2v[j] = vw2[tx * 8 + j]; }
        float vb20 = vb2[0];
#pragma unroll
        for (int i = 0; i < 4; ++i) {
            float p = 0.f;
#pragma unroll
            for (int j = 0; j < 8; ++j) p += silu_f(acc[i][j] + bb[j]) * w2v[j];
            p += __shfl_xor(p, 1);
            p += __shfl_xor(p, 2);
            p += __shfl_xor(p, 4);
            p += __shfl_xor(p, 8);
            float vs = p + vb20;
            if (tx == 0) {
                int n = n0 + ty * 4 + i;
                if (n < N) {
                    float cc = fmaxf(cnt[n], 1.0f);
#pragma unroll
                    for (int d = 0; d < 3; ++d) {
                        float vn = vs * vel[n * 3 + d];
                        float xn = x[n * 3 + d] + aggx[n * 3 + d] / cc + vn;  // CW = 1.0
                        vel[n * 3 + d] = vn;
                        x[n * 3 + d] = xn;
                    }
                }
            }
        }
    }

    // ---- phase B: h = silu([h,agg_h]@nw1 + nb1)@nw2 + nb2 ----
    float acc2[4][8];
#pragma unroll
    for (int i = 0; i < 4; ++i)
#pragma unroll
        for (int j = 0; j < 8; ++j) acc2[i][j] = 0.f;
    {
        const float* wp = &nw1[tx * 8];
#pragma unroll 4
        for (int k = 0; k < HID; ++k) {
            float4 w0 = *(const float4*)&wp[k * HID];
            float4 w1v = *(const float4*)&wp[k * HID + 4];
            float wv[8] = {w0.x, w0.y, w0.z, w0.w, w1v.x, w1v.y, w1v.z, w1v.w};
            float av[4];
#pragma unroll
            for (int i = 0; i < 4; ++i) av[i] = BH[ty * 4 + i][k];
#pragma unroll
            for (int i = 0; i < 4; ++i)
#pragma unroll
                for (int j = 0; j < 8; ++j) acc2[i][j] += av[i] * wv[j];
        }
        const float* wp2 = &nw1[128 * HID + tx * 8];
#pragma unroll 4
        for (int k = 0; k < HID; ++k) {
            float4 w0 = *(const float4*)&wp2[k * HID];
            float4 w1v = *(const float4*)&wp2[k * HID + 4];
            float wv[8] = {w0.x, w0.y, w0.z, w0.w, w1v.x, w1v.y, w1v.z, w1v.w};
            float av[4];
#pragma unroll
            for (int i = 0; i < 4; ++i) av[i] = BG[ty * 4 + i][k];
#pragma unroll
            for (int i = 0; i < 4; ++i)
#pragma unroll
                for (int j = 0; j < 8; ++j) acc2[i][j] += av[i] * wv[j];
        }
    }
    __syncthreads();  // done reading BH (h)
    {
        float bb[8];
#pragma unroll
        for (int j = 0; j < 8; ++j) bb[j] = nb1[tx * 8 + j];
#pragma unroll
        for (int i = 0; i < 4; ++i)
#pragma unroll
            for (int j = 0; j < 8; ++j)
                BH[ty * 4 + i][tx * 8 + j] = silu_f(acc2[i][j] + bb[j]);
    }
    __syncthreads();
    float acc3[4][8];
#pragma unroll
    for (int i = 0; i < 4; ++i)
#pragma unroll
        for (int j = 0; j < 8; ++j) acc3[i][j] = 0.f;
    {
        const float* wp = &nw2[tx * 8];
#pragma unroll 4
        for (int k = 0; k < HID; ++k) {
            float4 w0 = *(const float4*)&wp[k * HID];
            float4 w1v = *(const float4*)&wp[k * HID + 4];
            float wv[8] = {w0.x, w0.y, w0.z, w0.w, w1v.x, w1v.y, w1v.z, w1v.w};
            float av[4];
#pragma unroll
            for (int i = 0; i < 4; ++i) av[i] = BH[ty * 4 + i][k];
#pragma unroll
            for (int i = 0; i < 4; ++i)
#pragma unroll
                for (int j = 0; j < 8; ++j) acc3[i][j] += av[i] * wv[j];
        }
    }
    {
        float bb[8];
#pragma unroll
        for (int j = 0; j < 8; ++j) bb[j] = nb2[tx * 8 + j];
#pragma unroll
        for (int i = 0; i < 4; ++i) {
            int n = n0 + ty * 4 + i;
            if (n < N) {
#pragma unroll
                for (int j = 0; j < 8; ++j)
                    h[(size_t)n * HID + tx * 8 + j] = acc3[i][j] + bb[j];
            }
        }
    }
}

__global__ void k_proj(const float* __restrict__ h, const float* __restrict__ pw,
                       const float* __restrict__ pb, float* __restrict__ out, int N) {
    int idx = blockIdx.x * 256 + threadIdx.x;
    if (idx >= N * 3) return;
    int n = idx / 3, p = idx % 3;
    float s = pb[p];
    const float* hr = &h[(size_t)n * HID];
#pragma unroll 8
    for (int k = 0; k < HID; ++k) s += hr[k] * pw[k * 3 + p];
    out[idx] = s;
}

extern "C" void kernel_launch(void* const* d_in, const int* in_sizes, int n_in,
                              void* d_out, int out_size, void* d_ws, size_t ws_size,
                              hipStream_t stream)
{
    const float* h_in  = (const float*)d_in[0];
    const float* x_in  = (const float*)d_in[1];
    const float* v_in  = (const float*)d_in[2];
    const float* eattr = (const float*)d_in[3];
    const int*   edges = (const int*)d_in[4];
    const float* emb_w = (const float*)d_in[5];
    const float* emb_b = (const float*)d_in[6];
    const float* ew1   = (const float*)d_in[7];
    const float* eb1   = (const float*)d_in[8];
    const float* ew2   = (const float*)d_in[9];
    const float* eb2   = (const float*)d_in[10];
    const float* aw    = (const float*)d_in[11];
    const float* ab    = (const float*)d_in[12];
    const float* nw1   = (const float*)d_in[13];
    const float* nb1   = (const float*)d_in[14];
    const float* nw2   = (const float*)d_in[15];
    const float* nb2   = (const float*)d_in[16];
    const float* cw1   = (const float*)d_in[17];
    const float* cb1   = (const float*)d_in[18];
    const float* cw2   = (const float*)d_in[19];
    const float* vw1   = (const float*)d_in[20];
    const float* vb1   = (const float*)d_in[21];
    const float* vw2   = (const float*)d_in[22];
    const float* vb2   = (const float*)d_in[23];
    const float* pw    = (const float*)d_in[24];
    const float* pb    = (const float*)d_in[25];

    const int N = in_sizes[0] / 6;
    const int E = in_sizes[4] / 2;
    const int* rows = edges;
    const int* cols = edges + E;

    float* ws   = (float*)d_ws;
    float* hbuf = ws;  ws += (size_t)N * HID;
    float* aggh = ws;  ws += (size_t)N * HID;
    float* aggx = ws;  ws += (size_t)N * 3;
    float* xb   = ws;  ws += (size_t)N * 3;
    float* vb   = ws;  ws += (size_t)N * 3;
    float* cnt  = ws;  ws += N;
    float* outp = (float*)d_out;

    hipMemcpyAsync(xb, x_in, (size_t)N * 3 * sizeof(float), hipMemcpyDeviceToDevice, stream);
    hipMemcpyAsync(vb, v_in, (size_t)N * 3 * sizeof(float), hipMemcpyDeviceToDevice, stream);
    hipMemsetAsync(cnt, 0, N * sizeof(float), stream);
    k_count<<<(E + 255) / 256, 256, 0, stream>>>(rows, cnt, E);
    k_embed<<<(N * HID + 255) / 256, 256, 0, stream>>>(h_in, emb_w, emb_b, hbuf, N);

    for (int l = 0; l < 4; ++l) {
        hipMemsetAsync(aggh, 0, (size_t)N * HID * sizeof(float), stream);
        hipMemsetAsync(aggx, 0, (size_t)N * 3 * sizeof(float), stream);
        k_edge<<<(E + 63) / 64, 256, 0, stream>>>(
            hbuf, xb, eattr, rows, cols,
            ew1 + (size_t)l * 259 * HID, eb1 + l * HID,
            ew2 + (size_t)l * HID * HID, eb2 + l * HID,
            aw + l * HID, ab + l,
            cw1 + (size_t)l * HID * HID, cb1 + l * HID, cw2 + l * HID,
            aggh, aggx, E);
        k_node<<<(N + 63) / 64, 256, 0, stream>>>(
            hbuf, aggh, aggx, cnt, xb, vb,
            vw1 + (size_t)l * HID * HID, vb1 + l * HID, vw2 + l * HID, vb2 + l,
            nw1 + (size_t)l * 2 * HID * HID, nb1 + l * HID,
            nw2 + (size_t)l * HID * HID, nb2 + l * HID, N);
    }
    k_proj<<<(N * 3 + 255) / 256, 256, 0, stream>>>(hbuf, pw, pb, outp, N);
    hipMemcpyAsync(outp + (size_t)N * 3, xb, (size_t)N * 3 * sizeof(float), hipMemcpyDeviceToDevice, stream);
    hipMemcpyAsync(outp + (size_t)N * 6, vb, (size_t)N * 3 * sizeof(float), hipMemcpyDeviceToDevice, stream);
}

// Round 2
// 1537.671 us; speedup vs baseline: 2.0292x; 2.0292x over previous
//
#include <hip/hip_runtime.h>
#include <math.h>

#define HID 128

typedef __attribute__((ext_vector_type(8))) short bf16x8;
typedef __attribute__((ext_vector_type(4))) float f32x4;

__device__ __forceinline__ float silu_f(float v) {
    return v / (1.0f + __expf(-v));
}
__device__ __forceinline__ float sigmoid_f(float v) {
    return 1.0f / (1.0f + __expf(-v));
}
__device__ __forceinline__ unsigned short bf16hi(float f) {
    return (unsigned short)(__float_as_uint(f) >> 16);
}
__device__ __forceinline__ float bf16tof(unsigned short u) {
    return __uint_as_float(((unsigned int)u) << 16);
}

__global__ void k_count(const int* __restrict__ rows, float* __restrict__ cnt, int E) {
    int i = blockIdx.x * 256 + threadIdx.x;
    if (i < E) atomicAdd(&cnt[rows[i]], 1.0f);
}

__global__ void k_embed(const float* __restrict__ hin, const float* __restrict__ w,
                        const float* __restrict__ b, float* __restrict__ hout, int N) {
    int idx = blockIdx.x * 256 + threadIdx.x;
    if (idx >= N * HID) return;
    int n = idx >> 7, j = idx & 127;
    float s = b[j];
    const float* hr = &hin[n * 6];
#pragma unroll
    for (int k = 0; k < 6; ++k) s += hr[k] * w[k * HID + j];
    hout[idx] = s;
}

// pack weights into MFMA-B-fragment layout [K/8][128][8], split bf16 hi/lo.
// per layer: ew1 first 256 rows (32768), ew2 (16384), cw1 (16384) -> 65536 elems
__global__ void k_pack_w(const float* __restrict__ ew1, const float* __restrict__ ew2,
                         const float* __restrict__ cw1,
                         unsigned short* __restrict__ w1h, unsigned short* __restrict__ w1l,
                         unsigned short* __restrict__ w2h, unsigned short* __restrict__ w2l,
                         unsigned short* __restrict__ c1h, unsigned short* __restrict__ c1l) {
    int idx = blockIdx.x * 256 + threadIdx.x;
    if (idx >= 4 * 65536) return;
    int l = idx >> 16, r = idx & 65535;
    const float* src;
    unsigned short *dh, *dl;
    int k, n;
    if (r < 32768) {
        k = r >> 7; n = r & 127;
        src = ew1 + (size_t)l * 33152 + k * 128 + n;
        dh = w1h + (size_t)l * 32768; dl = w1l + (size_t)l * 32768;
    } else if (r < 49152) {
        int rr = r - 32768; k = rr >> 7; n = rr & 127;
        src = ew2 + (size_t)l * 16384 + k * 128 + n;
        dh = w2h + (size_t)l * 16384; dl = w2l + (size_t)l * 16384;
    } else {
        int rr = r - 49152; k = rr >> 7; n = rr & 127;
        src = cw1 + (size_t)l * 16384 + k * 128 + n;
        dh = c1h + (size_t)l * 16384; dl = c1l + (size_t)l * 16384;
    }
    float f = *src;
    unsigned short hi = bf16hi(f);
    float rem = f - bf16tof(hi);
    int di = (k >> 3) * 1024 + n * 8 + (k & 7);
    dh[di] = hi; dl[di] = bf16hi(rem);
}

// convert h [N,128] f32 -> hi/lo bf16 tables
__global__ void k_prep_h(const float* __restrict__ h, unsigned short* __restrict__ hhi,
                         unsigned short* __restrict__ hlo, int N) {
    int idx = blockIdx.x * 256 + threadIdx.x;
    if (idx >= N * HID) return;
    float f = h[idx];
    unsigned short hi = bf16hi(f);
    float rem = f - bf16tof(hi);
    hhi[idx] = hi; hlo[idx] = bf16hi(rem);
}

// MFMA edge kernel: 64 edges/block (4 waves x 16 edges), split-precision bf16x3
__global__ __launch_bounds__(256, 4) void k_edge_mfma(
    const unsigned short* __restrict__ hhi, const unsigned short* __restrict__ hlo,
    const float* __restrict__ x, const float* __restrict__ eattr,
    const int* __restrict__ rows, const int* __restrict__ cols,
    const unsigned short* __restrict__ w1h, const unsigned short* __restrict__ w1l,
    const float* __restrict__ ew1_tail, const float* __restrict__ eb1,
    const unsigned short* __restrict__ w2h, const unsigned short* __restrict__ w2l,
    const float* __restrict__ eb2,
    const float* __restrict__ aw, const float* __restrict__ ab,
    const unsigned short* __restrict__ c1h, const unsigned short* __restrict__ c1l,
    const float* __restrict__ cb1, const float* __restrict__ cw2,
    float* __restrict__ aggh, float* __restrict__ aggx, int E)
{
    __shared__ float sCD[64][4];
    __shared__ float sEA[64][2];
    __shared__ int sRow[64], sCol[64];
    __shared__ unsigned short tHi[4][16][136];   // per-wave activation buffer (hi)
    __shared__ unsigned short tLo[4][16][136];   // per-wave activation buffer (lo)

    const int t = threadIdx.x;
    const int wv = t >> 6, lane = t & 63;
    const int quad = lane >> 4, ln = lane & 15;
    const int e0 = blockIdx.x * 64;

    if (t < 64) {
        int eg = e0 + t;
        int ec = eg < E ? eg : E - 1;
        int r = rows[ec], c = cols[ec];
        sRow[t] = r; sCol[t] = c;
        float dx = x[r * 3 + 0] - x[c * 3 + 0];
        float dy = x[r * 3 + 1] - x[c * 3 + 1];
        float dz = x[r * 3 + 2] - x[c * 3 + 2];
        sCD[t][0] = dx; sCD[t][1] = dy; sCD[t][2] = dz;
        sCD[t][3] = dx * dx + dy * dy + dz * dz;
        sEA[t][0] = eattr[(size_t)ec * 2 + 0];
        sEA[t][1] = eattr[(size_t)ec * 2 + 1];
    }
    __syncthreads();

    const int eL = wv * 16 + ln;           // this lane's A-row edge (local)
    const int rowN = sRow[eL], colN = sCol[eL];

    // ---- GEMM1: t1 = e_in[0:256] @ ew1[0:256], K chunks of 32 ----
    f32x4 acc[8];
#pragma unroll
    for (int i = 0; i < 8; ++i) acc[i] = (f32x4){0.f, 0.f, 0.f, 0.f};
#pragma unroll 1
    for (int kc = 0; kc < 8; ++kc) {
        int kg = kc * 32 + quad * 8;
        int node = (kg < 128) ? rowN : colN;
        int ko = kg & 127;
        bf16x8 ahi = *(const bf16x8*)(hhi + (size_t)node * HID + ko);
        bf16x8 alo = *(const bf16x8*)(hlo + (size_t)node * HID + ko);
        const unsigned short* bh = w1h + (kc * 4 + quad) * 1024;
        const unsigned short* bl = w1l + (kc * 4 + quad) * 1024;
#pragma unroll
        for (int t8 = 0; t8 < 8; ++t8) {
            int n = t8 * 16 + ln;
            bf16x8 bhi = *(const bf16x8*)(bh + n * 8);
            bf16x8 blo = *(const bf16x8*)(bl + n * 8);
            acc[t8] = __builtin_amdgcn_mfma_f32_16x16x32_bf16(ahi, bhi, acc[t8], 0, 0, 0);
            acc[t8] = __builtin_amdgcn_mfma_f32_16x16x32_bf16(alo, bhi, acc[t8], 0, 0, 0);
            acc[t8] = __builtin_amdgcn_mfma_f32_16x16x32_bf16(ahi, blo, acc[t8], 0, 0, 0);
        }
    }
    // tail k=256..258 (radial, edge_attr) in fp32 + bias + silu -> LDS (A-layout, hi/lo)
#pragma unroll
    for (int t8 = 0; t8 < 8; ++t8) {
        int n = t8 * 16 + ln;
        float w6 = ew1_tail[n], w7 = ew1_tail[128 + n], w8 = ew1_tail[256 + n];
        float bb = eb1[n];
#pragma unroll
        for (int r = 0; r < 4; ++r) {
            int m = wv * 16 + quad * 4 + r;
            float v = acc[t8][r] + sCD[m][3] * w6 + sEA[m][0] * w7 + sEA[m][1] * w8 + bb;
            v = silu_f(v);
            unsigned short hi = bf16hi(v);
            float rem = v - bf16tof(hi);
            tHi[wv][quad * 4 + r][n] = hi;
            tLo[wv][quad * 4 + r][n] = bf16hi(rem);
        }
    }
    __syncthreads();

    // ---- GEMM2: t2 = t1 @ ew2 ----
    f32x4 acc2[8];
#pragma unroll
    for (int i = 0; i < 8; ++i) acc2[i] = (f32x4){0.f, 0.f, 0.f, 0.f};
#pragma unroll 1
    for (int kc = 0; kc < 4; ++kc) {
        bf16x8 ahi = *(const bf16x8*)&tHi[wv][ln][kc * 32 + quad * 8];
        bf16x8 alo = *(const bf16x8*)&tLo[wv][ln][kc * 32 + quad * 8];
        const unsigned short* bh = w2h + (kc * 4 + quad) * 1024;
        const unsigned short* bl = w2l + (kc * 4 + quad) * 1024;
#pragma unroll
        for (int t8 = 0; t8 < 8; ++t8) {
            int n = t8 * 16 + ln;
            bf16x8 bhi = *(const bf16x8*)(bh + n * 8);
            bf16x8 blo = *(const bf16x8*)(bl + n * 8);
            acc2[t8] = __builtin_amdgcn_mfma_f32_16x16x32_bf16(ahi, bhi, acc2[t8], 0, 0, 0);
            acc2[t8] = __builtin_amdgcn_mfma_f32_16x16x32_bf16(alo, bhi, acc2[t8], 0, 0, 0);
            acc2[t8] = __builtin_amdgcn_mfma_f32_16x16x32_bf16(ahi, blo, acc2[t8], 0, 0, 0);
        }
    }
    // silu + attention gate
    float pr[4] = {0.f, 0.f, 0.f, 0.f};
#pragma unroll
    for (int t8 = 0; t8 < 8; ++t8) {
        int n = t8 * 16 + ln;
        float bb = eb2[n], awn = aw[n];
#pragma unroll
        for (int r = 0; r < 4; ++r) {
            float v = silu_f(acc2[t8][r] + bb);
            acc2[t8][r] = v;
            pr[r] += v * awn;
        }
    }
    {
        float ab0 = ab[0];
#pragma unroll
        for (int r = 0; r < 4; ++r) {
            float p = pr[r];
            p += __shfl_xor(p, 1);
            p += __shfl_xor(p, 2);
            p += __shfl_xor(p, 4);
            p += __shfl_xor(p, 8);
            pr[r] = sigmoid_f(p + ab0);
        }
    }
    __syncthreads();
    // gated m -> LDS (for GEMM3) + agg_h atomics
#pragma unroll
    for (int t8 = 0; t8 < 8; ++t8) {
        int n = t8 * 16 + ln;
#pragma unroll
        for (int r = 0; r < 4; ++r) {
            float v = acc2[t8][r] * pr[r];
            unsigned short hi = bf16hi(v);
            float rem = v - bf16tof(hi);
            tHi[wv][quad * 4 + r][n] = hi;
            tLo[wv][quad * 4 + r][n] = bf16hi(rem);
            int m = wv * 16 + quad * 4 + r;
            int eg = e0 + m;
            if (eg < E) atomicAdd(&aggh[(size_t)sRow[m] * HID + n], v);
        }
    }
    __syncthreads();

    // ---- GEMM3: u = silu(m @ cw1 + cb1), wc = u @ cw2 ----
    f32x4 acc3[8];
#pragma unroll
    for (int i = 0; i < 8; ++i) acc3[i] = (f32x4){0.f, 0.f, 0.f, 0.f};
#pragma unroll 1
    for (int kc = 0; kc < 4; ++kc) {
        bf16x8 ahi = *(const bf16x8*)&tHi[wv][ln][kc * 32 + quad * 8];
        bf16x8 alo = *(const bf16x8*)&tLo[wv][ln][kc * 32 + quad * 8];
        const unsigned short* bh = c1h + (kc * 4 + quad) * 1024;
        const unsigned short* bl = c1l + (kc * 4 + quad) * 1024;
#pragma unroll
        for (int t8 = 0; t8 < 8; ++t8) {
            int n = t8 * 16 + ln;
            bf16x8 bhi = *(const bf16x8*)(bh + n * 8);
            bf16x8 blo = *(const bf16x8*)(bl + n * 8);
            acc3[t8] = __builtin_amdgcn_mfma_f32_16x16x32_bf16(ahi, bhi, acc3[t8], 0, 0, 0);
            acc3[t8] = __builtin_amdgcn_mfma_f32_16x16x32_bf16(alo, bhi, acc3[t8], 0, 0, 0);
            acc3[t8] = __builtin_amdgcn_mfma_f32_16x16x32_bf16(ahi, blo, acc3[t8], 0, 0, 0);
        }
    }
    {
        float pr3[4] = {0.f, 0.f, 0.f, 0.f};
#pragma unroll
        for (int t8 = 0; t8 < 8; ++t8) {
            int n = t8 * 16 + ln;
            float bb = cb1[n], cwn = cw2[n];
#pragma unroll
            for (int r = 0; r < 4; ++r) {
                float u = silu_f(acc3[t8][r] + bb);
                pr3[r] += u * cwn;
            }
        }
#pragma unroll
        for (int r = 0; r < 4; ++r) {
            float p = pr3[r];
            p += __shfl_xor(p, 1);
            p += __shfl_xor(p, 2);
            p += __shfl_xor(p, 4);
            p += __shfl_xor(p, 8);
            pr3[r] = p;
        }
        if (ln < 3) {
#pragma unroll
            for (int r = 0; r < 4; ++r) {
                int m = wv * 16 + quad * 4 + r;
                int eg = e0 + m;
                if (eg < E)
                    atomicAdd(&aggx[sRow[m] * 3 + ln], sCD[m][ln] * pr3[r]);
            }
        }
    }
}

// 64 nodes per block, 256 threads (fp32 — cheap relative to edges)
__global__ __launch_bounds__(256, 2) void k_node(
    float* __restrict__ h, const float* __restrict__ aggh,
    const float* __restrict__ aggx, const float* __restrict__ cnt,
    float* __restrict__ x, float* __restrict__ vel,
    const float* __restrict__ vw1, const float* __restrict__ vb1,
    const float* __restrict__ vw2, const float* __restrict__ vb2,
    const float* __restrict__ nw1, const float* __restrict__ nb1,
    const float* __restrict__ nw2, const float* __restrict__ nb2,
    int N)
{
    __shared__ __align__(16) float BH[64][132];
    __shared__ __align__(16) float BG[64][132];
    const int t = threadIdx.x;
    const int tx = t & 15, ty = t >> 4;
    const int n0 = blockIdx.x * 64;

    for (int idx = t; idx < 64 * 32; idx += 256) {
        int r = idx >> 5, c4 = idx & 31;
        int n = n0 + r;
        float4 v0 = make_float4(0.f, 0.f, 0.f, 0.f), v1 = v0;
        if (n < N) {
            v0 = *(const float4*)&h[(size_t)n * HID + c4 * 4];
            v1 = *(const float4*)&aggh[(size_t)n * HID + c4 * 4];
        }
        *(float4*)&BH[r][c4 * 4] = v0;
        *(float4*)&BG[r][c4 * 4] = v1;
    }
    __syncthreads();

    {
        float acc[4][8];
#pragma unroll
        for (int i = 0; i < 4; ++i)
#pragma unroll
            for (int j = 0; j < 8; ++j) acc[i][j] = 0.f;
        const float* wp = &vw1[tx * 8];
#pragma unroll 4
        for (int k = 0; k < HID; ++k) {
            float4 w0 = *(const float4*)&wp[k * HID];
            float4 w1v = *(const float4*)&wp[k * HID + 4];
            float wv[8] = {w0.x, w0.y, w0.z, w0.w, w1v.x, w1v.y, w1v.z, w1v.w};
            float av[4];
#pragma unroll
            for (int i = 0; i < 4; ++i) av[i] = BH[ty * 4 + i][k];
#pragma unroll
            for (int i = 0; i < 4; ++i)
#pragma unroll
                for (int j = 0; j < 8; ++j) acc[i][j] += av[i] * wv[j];
        }
        float bb[8], w2v[8];
#pragma unroll
        for (int j = 0; j < 8; ++j) { bb[j] = vb1[tx * 8 + j]; w2v[j] = vw2[tx * 8 + j]; }
        float vb20 = vb2[0];
#pragma unroll
        for (int i = 0; i < 4; ++i) {
            float p = 0.f;
#pragma unroll
            for (int j = 0; j < 8; ++j) p += silu_f(acc[i][j] + bb[j]) * w2v[j];
            p += __shfl_xor(p, 1);
            p += __shfl_xor(p, 2);
            p += __shfl_xor(p, 4);
            p += __shfl_xor(p, 8);
            float vs = p + vb20;
            if (tx == 0) {
                int n = n0 + ty * 4 + i;
                if (n < N) {
                    float cc = fmaxf(cnt[n], 1.0f);
#pragma unroll
                    for (int d = 0; d < 3; ++d) {
                        float vn = vs * vel[n * 3 + d];
                        float xn = x[n * 3 + d] + aggx[n * 3 + d] / cc + vn;
                        vel[n * 3 + d] = vn;
                        x[n * 3 + d] = xn;
                    }
                }
            }
        }
    }

    float acc2[4][8];
#pragma unroll
    for (int i = 0; i < 4; ++i)
#pragma unroll
        for (int j = 0; j < 8; ++j) acc2[i][j] = 0.f;
    {
        const float* wp = &nw1[tx * 8];
#pragma unroll 4
        for (int k = 0; k < HID; ++k) {
            float4 w0 = *(const float4*)&wp[k * HID];
            float4 w1v = *(const float4*)&wp[k * HID + 4];
            float wv[8] = {w0.x, w0.y, w0.z, w0.w, w1v.x, w1v.y, w1v.z, w1v.w};
            float av[4];
#pragma unroll
            for (int i = 0; i < 4; ++i) av[i] = BH[ty * 4 + i][k];
#pragma unroll
            for (int i = 0; i < 4; ++i)
#pragma unroll
                for (int j = 0; j < 8; ++j) acc2[i][j] += av[i] * wv[j];
        }
        const float* wp2 = &nw1[128 * HID + tx * 8];
#pragma unroll 4
        for (int k = 0; k < HID; ++k) {
            float4 w0 = *(const float4*)&wp2[k * HID];
            float4 w1v = *(const float4*)&wp2[k * HID + 4];
            float wv[8] = {w0.x, w0.y, w0.z, w0.w, w1v.x, w1v.y, w1v.z, w1v.w};
            float av[4];
#pragma unroll
            for (int i = 0; i < 4; ++i) av[i] = BG[ty * 4 + i][k];
#pragma unroll
            for (int i = 0; i < 4; ++i)
#pragma unroll
                for (int j = 0; j < 8; ++j) acc2[i][j] += av[i] * wv[j];
        }
    }
    __syncthreads();
    {
        float bb[8];
#pragma unroll
        for (int j = 0; j < 8; ++j) bb[j] = nb1[tx * 8 + j];
#pragma unroll
        for (int i = 0; i < 4; ++i)
#pragma unroll
            for (int j = 0; j < 8; ++j)
                BH[ty * 4 + i][tx * 8 + j] = silu_f(acc2[i][j] + bb[j]);
    }
    __syncthreads();
    float acc3[4][8];
#pragma unroll
    for (int i = 0; i < 4; ++i)
#pragma unroll
        for (int j = 0; j < 8; ++j) acc3[i][j] = 0.f;
    {
        const float* wp = &nw2[tx * 8];
#pragma unroll 4
        for (int k = 0; k < HID; ++k) {
            float4 w0 = *(const float4*)&wp[k * HID];
            float4 w1v = *(const float4*)&wp[k * HID + 4];
            float wv[8] = {w0.x, w0.y, w0.z, w0.w, w1v.x, w1v.y, w1v.z, w1v.w};
            float av[4];
#pragma unroll
            for (int i = 0; i < 4; ++i) av[i] = BH[ty * 4 + i][k];
#pragma unroll
            for (int i = 0; i < 4; ++i)
#pragma unroll
                for (int j = 0; j < 8; ++j) acc3[i][j] += av[i] * wv[j];
        }
    }
    {
        float bb[8];
#pragma unroll
        for (int j = 0; j < 8; ++j) bb[j] = nb2[tx * 8 + j];
#pragma unroll
        for (int i = 0; i < 4; ++i) {
            int n = n0 + ty * 4 + i;
            if (n < N) {
#pragma unroll
                for (int j = 0; j < 8; ++j)
                    h[(size_t)n * HID + tx * 8 + j] = acc3[i][j] + bb[j];
            }
        }
    }
}

__global__ void k_proj(const float* __restrict__ h, const float* __restrict__ pw,
                       const float* __restrict__ pb, float* __restrict__ out, int N) {
    int idx = blockIdx.x * 256 + threadIdx.x;
    if (idx >= N * 3) return;
    int n = idx / 3, p = idx % 3;
    float s = pb[p];
    const float* hr = &h[(size_t)n * HID];
#pragma unroll 8
    for (int k = 0; k < HID; ++k) s += hr[k] * pw[k * 3 + p];
    out[idx] = s;
}

extern "C" void kernel_launch(void* const* d_in, const int* in_sizes, int n_in,
                              void* d_out, int out_size, void* d_ws, size_t ws_size,
                              hipStream_t stream)
{
    const float* h_in  = (const float*)d_in[0];
    const float* x_in  = (const float*)d_in[1];
    const float* v_in  = (const float*)d_in[2];
    const float* eattr = (const float*)d_in[3];
    const int*   edges = (const int*)d_in[4];
    const float* emb_w = (const float*)d_in[5];
    const float* emb_b = (const float*)d_in[6];
    const float* ew1   = (const float*)d_in[7];
    const float* eb1   = (const float*)d_in[8];
    const float* ew2   = (const float*)d_in[9];
    const float* eb2   = (const float*)d_in[10];
    const float* aw    = (const float*)d_in[11];
    const float* ab    = (const float*)d_in[12];
    const float* nw1   = (const float*)d_in[13];
    const float* nb1   = (const float*)d_in[14];
    const float* nw2   = (const float*)d_in[15];
    const float* nb2   = (const float*)d_in[16];
    const float* cw1   = (const float*)d_in[17];
    const float* cb1   = (const float*)d_in[18];
    const float* cw2   = (const float*)d_in[19];
    const float* vw1   = (const float*)d_in[20];
    const float* vb1   = (const float*)d_in[21];
    const float* vw2   = (const float*)d_in[22];
    const float* vb2   = (const float*)d_in[23];
    const float* pw    = (const float*)d_in[24];
    const float* pb    = (const float*)d_in[25];

    const int N = in_sizes[0] / 6;
    const int E = in_sizes[4] / 2;
    const int* rows = edges;
    const int* cols = edges + E;

    float* ws   = (float*)d_ws;
    float* hbuf = ws;  ws += (size_t)N * HID;
    float* aggh = ws;  ws += (size_t)N * HID;
    float* aggx = ws;  ws += (size_t)N * 3;
    float* xb   = ws;  ws += (size_t)N * 3;
    float* vb   = ws;  ws += (size_t)N * 3;
    float* cnt  = ws;  ws += N;
    unsigned short* us = (unsigned short*)ws;
    unsigned short* hhi = us;  us += (size_t)N * HID;
    unsigned short* hlo = us;  us += (size_t)N * HID;
    unsigned short* w1h = us;  us += 4 * 32768;
    unsigned short* w1l = us;  us += 4 * 32768;
    unsigned short* w2h = us;  us += 4 * 16384;
    unsigned short* w2l = us;  us += 4 * 16384;
    unsigned short* c1h = us;  us += 4 * 16384;
    unsigned short* c1l = us;  us += 4 * 16384;
    float* outp = (float*)d_out;

    hipMemcpyAsync(xb, x_in, (size_t)N * 3 * sizeof(float), hipMemcpyDeviceToDevice, stream);
    hipMemcpyAsync(vb, v_in, (size_t)N * 3 * sizeof(float), hipMemcpyDeviceToDevice, stream);
    hipMemsetAsync(cnt, 0, N * sizeof(float), stream);
    k_count<<<(E + 255) / 256, 256, 0, stream>>>(rows, cnt, E);
    k_pack_w<<<(4 * 65536 + 255) / 256, 256, 0, stream>>>(ew1, ew2, cw1, w1h, w1l, w2h, w2l, c1h, c1l);
    k_embed<<<(N * HID + 255) / 256, 256, 0, stream>>>(h_in, emb_w, emb_b, hbuf, N);

    for (int l = 0; l < 4; ++l) {
        k_prep_h<<<(N * HID + 255) / 256, 256, 0, stream>>>(hbuf, hhi, hlo, N);
        hipMemsetAsync(aggh, 0, (size_t)N * HID * sizeof(float), stream);
        hipMemsetAsync(aggx, 0, (size_t)N * 3 * sizeof(float), stream);
        k_edge_mfma<<<(E + 63) / 64, 256, 0, stream>>>(
            hhi, hlo, xb, eattr, rows, cols,
            w1h + (size_t)l * 32768, w1l + (size_t)l * 32768,
            ew1 + (size_t)l * 33152 + 256 * HID, eb1 + l * HID,
            w2h + (size_t)l * 16384, w2l + (size_t)l * 16384, eb2 + l * HID,
            aw + l * HID, ab + l,
            c1h + (size_t)l * 16384, c1l + (size_t)l * 16384,
            cb1 + l * HID, cw2 + l * HID,
            aggh, aggx, E);
        k_node<<<(N + 63) / 64, 256, 0, stream>>>(
            hbuf, aggh, aggx, cnt, xb, vb,
            vw1 + (size_t)l * HID * HID, vb1 + l * HID, vw2 + l * HID, vb2 + l,
            nw1 + (size_t)l * 2 * HID * HID, nb1 + l * HID,
            nw2 + (size_t)l * HID * HID, nb2 + l * HID, N);
    }
    k_proj<<<(N * 3 + 255) / 256, 256, 0, stream>>>(hbuf, pw, pb, outp, N);
    hipMemcpyAsync(outp + (size_t)N * 3, xb, (size_t)N * 3 * sizeof(float), hipMemcpyDeviceToDevice, stream);
    hipMemcpyAsync(outp + (size_t)N * 6, vb, (size_t)N * 3 * sizeof(float), hipMemcpyDeviceToDevice, stream);
}

// Round 3
// 1537.599 us; speedup vs baseline: 2.0293x; 1.0000x over previous
//
#include <hip/hip_runtime.h>
#include <math.h>

#define HID 128

typedef __attribute__((ext_vector_type(8))) short bf16x8;
typedef __attribute__((ext_vector_type(4))) float f32x4;

__device__ __forceinline__ float silu_f(float v) {
    return v / (1.0f + __expf(-v));
}
__device__ __forceinline__ float sigmoid_f(float v) {
    return 1.0f / (1.0f + __expf(-v));
}
__device__ __forceinline__ unsigned short bf16hi(float f) {
    return (unsigned short)(__float_as_uint(f) >> 16);
}
__device__ __forceinline__ float bf16tof(unsigned short u) {
    return __uint_as_float(((unsigned int)u) << 16);
}

__device__ __forceinline__ void stage16(const unsigned short* g, unsigned short* l) {
    __builtin_amdgcn_global_load_lds(
        (const __attribute__((address_space(1))) unsigned int*)g,
        (__attribute__((address_space(3))) unsigned int*)l, 16, 0, 0);
}
// copy one 16 KB weight chunk (8192 shorts) global -> LDS, 256 threads
__device__ __forceinline__ void stage_chunk(const unsigned short* __restrict__ g,
                                            unsigned short* l, int t) {
    int wv = t >> 6, lane = t & 63;
    const unsigned short* gs = g + wv * 2048 + lane * 8;
    unsigned short* ls = l + wv * 2048 + lane * 8;
#pragma unroll
    for (int i = 0; i < 4; ++i)
        stage16(gs + i * 512, ls + i * 512);
}

__global__ void k_count(const int* __restrict__ rows, float* __restrict__ cnt, int E) {
    int i = blockIdx.x * 256 + threadIdx.x;
    if (i < E) atomicAdd(&cnt[rows[i]], 1.0f);
}

__global__ void k_embed(const float* __restrict__ hin, const float* __restrict__ w,
                        const float* __restrict__ b, float* __restrict__ hout, int N) {
    int idx = blockIdx.x * 256 + threadIdx.x;
    if (idx >= N * HID) return;
    int n = idx >> 7, j = idx & 127;
    float s = b[j];
    const float* hr = &hin[n * 6];
#pragma unroll
    for (int k = 0; k < 6; ++k) s += hr[k] * w[k * HID + j];
    hout[idx] = s;
}

// pack weights into chunked MFMA-B layout, interleaved hi/lo:
// chunk (K=32 rows) = [4 quads(k8)][2 (hi,lo)][128 n][8 k] = 8192 shorts = 16 KB
// w1: 8 chunks/layer (65536 shorts); w2,c1: 4 chunks/layer (32768 shorts)
__global__ void k_pack_w(const float* __restrict__ ew1, const float* __restrict__ ew2,
                         const float* __restrict__ cw1,
                         unsigned short* __restrict__ w1p, unsigned short* __restrict__ w2p,
                         unsigned short* __restrict__ c1p) {
    int idx = blockIdx.x * 256 + threadIdx.x;
    if (idx >= 4 * 65536) return;
    int l = idx >> 16, r = idx & 65535;
    const float* src;
    unsigned short* dst;
    int k, n;
    if (r < 32768) {
        k = r >> 7; n = r & 127;
        src = ew1 + (size_t)l * 33152 + k * 128 + n;
        dst = w1p + (size_t)l * 65536;
    } else if (r < 49152) {
        int rr = r - 32768; k = rr >> 7; n = rr & 127;
        src = ew2 + (size_t)l * 16384 + k * 128 + n;
        dst = w2p + (size_t)l * 32768;
    } else {
        int rr = r - 49152; k = rr >> 7; n = rr & 127;
        src = cw1 + (size_t)l * 16384 + k * 128 + n;
        dst = c1p + (size_t)l * 32768;
    }
    float f = *src;
    unsigned short hi = bf16hi(f);
    float rem = f - bf16tof(hi);
    int s = k >> 3;
    int base = s * 2048 + n * 8 + (k & 7);
    dst[base] = hi;
    dst[base + 1024] = bf16hi(rem);
}

__global__ void k_prep_h(const float* __restrict__ h, unsigned short* __restrict__ hhi,
                         unsigned short* __restrict__ hlo, int N) {
    int idx = blockIdx.x * 256 + threadIdx.x;
    if (idx >= N * HID) return;
    float f = h[idx];
    unsigned short hi = bf16hi(f);
    float rem = f - bf16tof(hi);
    hhi[idx] = hi; hlo[idx] = bf16hi(rem);
}

// MFMA edge kernel: 64 edges/block (4 waves x 16 edges), split bf16 x3,
// weights double-buffer staged in LDS (shared by 4 waves)
__global__ __launch_bounds__(256, 2) void k_edge_mfma(
    const unsigned short* __restrict__ hhi, const unsigned short* __restrict__ hlo,
    const float* __restrict__ x, const float* __restrict__ eattr,
    const int* __restrict__ rows, const int* __restrict__ cols,
    const unsigned short* __restrict__ w1p, const float* __restrict__ ew1_tail,
    const float* __restrict__ eb1,
    const unsigned short* __restrict__ w2p, const float* __restrict__ eb2,
    const float* __restrict__ aw, const float* __restrict__ ab,
    const unsigned short* __restrict__ c1p, const float* __restrict__ cb1,
    const float* __restrict__ cw2,
    float* __restrict__ aggh, float* __restrict__ aggx, int E)
{
    __shared__ __align__(16) unsigned short sW[2][8192];      // weight chunk dbuf (32 KB)
    __shared__ __align__(16) unsigned short tHi[4][16][136];  // per-wave act hi
    __shared__ __align__(16) unsigned short tLo[4][16][136];  // per-wave act lo
    __shared__ float sCD[64][4];
    __shared__ float sEA[64][2];
    __shared__ int sRow[64], sCol[64];

    const int t = threadIdx.x;
    const int wv = t >> 6, lane = t & 63;
    const int quad = lane >> 4, ln = lane & 15;
    const int e0 = blockIdx.x * 64;

    if (t < 64) {
        int eg = e0 + t;
        int ec = eg < E ? eg : E - 1;
        int r = rows[ec], c = cols[ec];
        sRow[t] = r; sCol[t] = c;
        float dx = x[r * 3 + 0] - x[c * 3 + 0];
        float dy = x[r * 3 + 1] - x[c * 3 + 1];
        float dz = x[r * 3 + 2] - x[c * 3 + 2];
        sCD[t][0] = dx; sCD[t][1] = dy; sCD[t][2] = dz;
        sCD[t][3] = dx * dx + dy * dy + dz * dz;
        sEA[t][0] = eattr[(size_t)ec * 2 + 0];
        sEA[t][1] = eattr[(size_t)ec * 2 + 1];
    }
    stage_chunk(w1p, sW[0], t);     // prefetch chunk 0
    __syncthreads();

    const int eL = wv * 16 + ln;
    const int rowN = sRow[eL], colN = sCol[eL];

    // ---- GEMM1: t1 = e_in[0:256] @ ew1[0:256] ----
    f32x4 acc[8];
#pragma unroll
    for (int i = 0; i < 8; ++i) acc[i] = (f32x4){0.f, 0.f, 0.f, 0.f};
#pragma unroll 1
    for (int kc = 0; kc < 8; ++kc) {
        const int p = kc & 1;
        if (kc < 7) stage_chunk(w1p + (kc + 1) * 8192, sW[p ^ 1], t);
        else        stage_chunk(w2p, sW[p ^ 1], t);
        int kg = kc * 32 + quad * 8;
        int node = (kg < 128) ? rowN : colN;
        int ko = kg & 127;
        bf16x8 ahi = *(const bf16x8*)(hhi + (size_t)node * HID + ko);
        bf16x8 alo = *(const bf16x8*)(hlo + (size_t)node * HID + ko);
        const unsigned short* bq = &sW[p][quad * 2048 + ln * 8];
#pragma unroll
        for (int t8 = 0; t8 < 8; ++t8) {
            bf16x8 bhi = *(const bf16x8*)(bq + t8 * 128);
            bf16x8 blo = *(const bf16x8*)(bq + 1024 + t8 * 128);
            acc[t8] = __builtin_amdgcn_mfma_f32_16x16x32_bf16(ahi, bhi, acc[t8], 0, 0, 0);
            acc[t8] = __builtin_amdgcn_mfma_f32_16x16x32_bf16(alo, bhi, acc[t8], 0, 0, 0);
            acc[t8] = __builtin_amdgcn_mfma_f32_16x16x32_bf16(ahi, blo, acc[t8], 0, 0, 0);
        }
        __syncthreads();
    }
    // tail k=256..258 (radial, edge_attr) fp32 + bias + silu -> act LDS
#pragma unroll
    for (int t8 = 0; t8 < 8; ++t8) {
        int n = t8 * 16 + ln;
        float w6 = ew1_tail[n], w7 = ew1_tail[128 + n], w8 = ew1_tail[256 + n];
        float bb = eb1[n];
#pragma unroll
        for (int r = 0; r < 4; ++r) {
            int m = wv * 16 + quad * 4 + r;
            float v = acc[t8][r] + sCD[m][3] * w6 + sEA[m][0] * w7 + sEA[m][1] * w8 + bb;
            v = silu_f(v);
            unsigned short hi = bf16hi(v);
            float rem = v - bf16tof(hi);
            tHi[wv][quad * 4 + r][n] = hi;
            tLo[wv][quad * 4 + r][n] = bf16hi(rem);
        }
    }
    __syncthreads();

    // ---- GEMM2: t2 = t1 @ ew2 ----  (sW[0] already holds w2 chunk 0)
    f32x4 acc2[8];
#pragma unroll
    for (int i = 0; i < 8; ++i) acc2[i] = (f32x4){0.f, 0.f, 0.f, 0.f};
#pragma unroll 1
    for (int kc = 0; kc < 4; ++kc) {
        const int p = kc & 1;
        if (kc < 3) stage_chunk(w2p + (kc + 1) * 8192, sW[p ^ 1], t);
        else        stage_chunk(c1p, sW[p ^ 1], t);
        bf16x8 ahi = *(const bf16x8*)&tHi[wv][ln][kc * 32 + quad * 8];
        bf16x8 alo = *(const bf16x8*)&tLo[wv][ln][kc * 32 + quad * 8];
        const unsigned short* bq = &sW[p][quad * 2048 + ln * 8];
#pragma unroll
        for (int t8 = 0; t8 < 8; ++t8) {
            bf16x8 bhi = *(const bf16x8*)(bq + t8 * 128);
            bf16x8 blo = *(const bf16x8*)(bq + 1024 + t8 * 128);
            acc2[t8] = __builtin_amdgcn_mfma_f32_16x16x32_bf16(ahi, bhi, acc2[t8], 0, 0, 0);
            acc2[t8] = __builtin_amdgcn_mfma_f32_16x16x32_bf16(alo, bhi, acc2[t8], 0, 0, 0);
            acc2[t8] = __builtin_amdgcn_mfma_f32_16x16x32_bf16(ahi, blo, acc2[t8], 0, 0, 0);
        }
        __syncthreads();
    }
    // silu + attention gate
    float pr[4] = {0.f, 0.f, 0.f, 0.f};
#pragma unroll
    for (int t8 = 0; t8 < 8; ++t8) {
        int n = t8 * 16 + ln;
        float bb = eb2[n], awn = aw[n];
#pragma unroll
        for (int r = 0; r < 4; ++r) {
            float v = silu_f(acc2[t8][r] + bb);
            acc2[t8][r] = v;
            pr[r] += v * awn;
        }
    }
    {
        float ab0 = ab[0];
#pragma unroll
        for (int r = 0; r < 4; ++r) {
            float p = pr[r];
            p += __shfl_xor(p, 1);
            p += __shfl_xor(p, 2);
            p += __shfl_xor(p, 4);
            p += __shfl_xor(p, 8);
            pr[r] = sigmoid_f(p + ab0);
        }
    }
    // gated m -> act LDS + agg_h atomics
#pragma unroll
    for (int t8 = 0; t8 < 8; ++t8) {
        int n = t8 * 16 + ln;
#pragma unroll
        for (int r = 0; r < 4; ++r) {
            float v = acc2[t8][r] * pr[r];
            unsigned short hi = bf16hi(v);
            float rem = v - bf16tof(hi);
            tHi[wv][quad * 4 + r][n] = hi;
            tLo[wv][quad * 4 + r][n] = bf16hi(rem);
            int m = wv * 16 + quad * 4 + r;
            int eg = e0 + m;
            if (eg < E) atomicAdd(&aggh[(size_t)sRow[m] * HID + n], v);
        }
    }
    __syncthreads();

    // ---- GEMM3: u = silu(m @ cw1 + cb1), wc = u @ cw2 ----  (sW[0] holds c1 chunk 0)
    f32x4 acc3[8];
#pragma unroll
    for (int i = 0; i < 8; ++i) acc3[i] = (f32x4){0.f, 0.f, 0.f, 0.f};
#pragma unroll 1
    for (int kc = 0; kc < 4; ++kc) {
        const int p = kc & 1;
        if (kc < 3) stage_chunk(c1p + (kc + 1) * 8192, sW[p ^ 1], t);
        bf16x8 ahi = *(const bf16x8*)&tHi[wv][ln][kc * 32 + quad * 8];
        bf16x8 alo = *(const bf16x8*)&tLo[wv][ln][kc * 32 + quad * 8];
        const unsigned short* bq = &sW[p][quad * 2048 + ln * 8];
#pragma unroll
        for (int t8 = 0; t8 < 8; ++t8) {
            bf16x8 bhi = *(const bf16x8*)(bq + t8 * 128);
            bf16x8 blo = *(const bf16x8*)(bq + 1024 + t8 * 128);
            acc3[t8] = __builtin_amdgcn_mfma_f32_16x16x32_bf16(ahi, bhi, acc3[t8], 0, 0, 0);
            acc3[t8] = __builtin_amdgcn_mfma_f32_16x16x32_bf16(alo, bhi, acc3[t8], 0, 0, 0);
            acc3[t8] = __builtin_amdgcn_mfma_f32_16x16x32_bf16(ahi, blo, acc3[t8], 0, 0, 0);
        }
        if (kc < 3) __syncthreads();
    }
    {
        float pr3[4] = {0.f, 0.f, 0.f, 0.f};
#pragma unroll
        for (int t8 = 0; t8 < 8; ++t8) {
            int n = t8 * 16 + ln;
            float bb = cb1[n], cwn = cw2[n];
#pragma unroll
            for (int r = 0; r < 4; ++r) {
                float u = silu_f(acc3[t8][r] + bb);
                pr3[r] += u * cwn;
            }
        }
#pragma unroll
        for (int r = 0; r < 4; ++r) {
            float p = pr3[r];
            p += __shfl_xor(p, 1);
            p += __shfl_xor(p, 2);
            p += __shfl_xor(p, 4);
            p += __shfl_xor(p, 8);
            pr3[r] = p;
        }
        if (ln < 3) {
#pragma unroll
            for (int r = 0; r < 4; ++r) {
                int m = wv * 16 + quad * 4 + r;
                int eg = e0 + m;
                if (eg < E)
                    atomicAdd(&aggx[sRow[m] * 3 + ln], sCD[m][ln] * pr3[r]);
            }
        }
    }
}

// 64 nodes per block, 256 threads (fp32)
__global__ __launch_bounds__(256, 2) void k_node(
    float* __restrict__ h, const float* __restrict__ aggh,
    const float* __restrict__ aggx, const float* __restrict__ cnt,
    float* __restrict__ x, float* __restrict__ vel,
    const float* __restrict__ vw1, const float* __restrict__ vb1,
    const float* __restrict__ vw2, const float* __restrict__ vb2,
    const float* __restrict__ nw1, const float* __restrict__ nb1,
    const float* __restrict__ nw2, const float* __restrict__ nb2,
    int N)
{
    __shared__ __align__(16) float BH[64][132];
    __shared__ __align__(16) float BG[64][132];
    const int t = threadIdx.x;
    const int tx = t & 15, ty = t >> 4;
    const int n0 = blockIdx.x * 64;

    for (int idx = t; idx < 64 * 32; idx += 256) {
        int r = idx >> 5, c4 = idx & 31;
        int n = n0 + r;
        float4 v0 = make_float4(0.f, 0.f, 0.f, 0.f), v1 = v0;
        if (n < N) {
            v0 = *(const float4*)&h[(size_t)n * HID + c4 * 4];
            v1 = *(const float4*)&aggh[(size_t)n * HID + c4 * 4];
        }
        *(float4*)&BH[r][c4 * 4] = v0;
        *(float4*)&BG[r][c4 * 4] = v1;
    }
    __syncthreads();

    {
        float acc[4][8];
#pragma unroll
        for (int i = 0; i < 4; ++i)
#pragma unroll
            for (int j = 0; j < 8; ++j) acc[i][j] = 0.f;
        const float* wp = &vw1[tx * 8];
#pragma unroll 4
        for (int k = 0; k < HID; ++k) {
            float4 w0 = *(const float4*)&wp[k * HID];
            float4 w1v = *(const float4*)&wp[k * HID + 4];
            float wv[8] = {w0.x, w0.y, w0.z, w0.w, w1v.x, w1v.y, w1v.z, w1v.w};
            float av[4];
#pragma unroll
            for (int i = 0; i < 4; ++i) av[i] = BH[ty * 4 + i][k];
#pragma unroll
            for (int i = 0; i < 4; ++i)
#pragma unroll
                for (int j = 0; j < 8; ++j) acc[i][j] += av[i] * wv[j];
        }
        float bb[8], w2v[8];
#pragma unroll
        for (int j = 0; j < 8; ++j) { bb[j] = vb1[tx * 8 + j]; w2v[j] = vw2[tx * 8 + j]; }
        float vb20 = vb2[0];
#pragma unroll
        for (int i = 0; i < 4; ++i) {
            float p = 0.f;
#pragma unroll
            for (int j = 0; j < 8; ++j) p += silu_f(acc[i][j] + bb[j]) * w2v[j];
            p += __shfl_xor(p, 1);
            p += __shfl_xor(p, 2);
            p += __shfl_xor(p, 4);
            p += __shfl_xor(p, 8);
            float vs = p + vb20;
            if (tx == 0) {
                int n = n0 + ty * 4 + i;
                if (n < N) {
                    float cc = fmaxf(cnt[n], 1.0f);
#pragma unroll
                    for (int d = 0; d < 3; ++d) {
                        float vn = vs * vel[n * 3 + d];
                        float xn = x[n * 3 + d] + aggx[n * 3 + d] / cc + vn;
                        vel[n * 3 + d] = vn;
                        x[n * 3 + d] = xn;
                    }
                }
            }
        }
    }

    float acc2[4][8];
#pragma unroll
    for (int i = 0; i < 4; ++i)
#pragma unroll
        for (int j = 0; j < 8; ++j) acc2[i][j] = 0.f;
    {
        const float* wp = &nw1[tx * 8];
#pragma unroll 4
        for (int k = 0; k < HID; ++k) {
            float4 w0 = *(const float4*)&wp[k * HID];
            float4 w1v = *(const float4*)&wp[k * HID + 4];
            float wv[8] = {w0.x, w0.y, w0.z, w0.w, w1v.x, w1v.y, w1v.z, w1v.w};
            float av[4];
#pragma unroll
            for (int i = 0; i < 4; ++i) av[i] = BH[ty * 4 + i][k];
#pragma unroll
            for (int i = 0; i < 4; ++i)
#pragma unroll
                for (int j = 0; j < 8; ++j) acc2[i][j] += av[i] * wv[j];
        }
        const float* wp2 = &nw1[128 * HID + tx * 8];
#pragma unroll 4
        for (int k = 0; k < HID; ++k) {
            float4 w0 = *(const float4*)&wp2[k * HID];
            float4 w1v = *(const float4*)&wp2[k * HID + 4];
            float wv[8] = {w0.x, w0.y, w0.z, w0.w, w1v.x, w1v.y, w1v.z, w1v.w};
            float av[4];
#pragma unroll
            for (int i = 0; i < 4; ++i) av[i] = BG[ty * 4 + i][k];
#pragma unroll
            for (int i = 0; i < 4; ++i)
#pragma unroll
                for (int j = 0; j < 8; ++j) acc2[i][j] += av[i] * wv[j];
        }
    }
    __syncthreads();
    {
        float bb[8];
#pragma unroll
        for (int j = 0; j < 8; ++j) bb[j] = nb1[tx * 8 + j];
#pragma unroll
        for (int i = 0; i < 4; ++i)
#pragma unroll
            for (int j = 0; j < 8; ++j)
                BH[ty * 4 + i][tx * 8 + j] = silu_f(acc2[i][j] + bb[j]);
    }
    __syncthreads();
    float acc3[4][8];
#pragma unroll
    for (int i = 0; i < 4; ++i)
#pragma unroll
        for (int j = 0; j < 8; ++j) acc3[i][j] = 0.f;
    {
        const float* wp = &nw2[tx * 8];
#pragma unroll 4
        for (int k = 0; k < HID; ++k) {
            float4 w0 = *(const float4*)&wp[k * HID];
            float4 w1v = *(const float4*)&wp[k * HID + 4];
            float wv[8] = {w0.x, w0.y, w0.z, w0.w, w1v.x, w1v.y, w1v.z, w1v.w};
            float av[4];
#pragma unroll
            for (int i = 0; i < 4; ++i) av[i] = BH[ty * 4 + i][k];
#pragma unroll
            for (int i = 0; i < 4; ++i)
#pragma unroll
                for (int j = 0; j < 8; ++j) acc3[i][j] += av[i] * wv[j];
        }
    }
    {
        float bb[8];
#pragma unroll
        for (int j = 0; j < 8; ++j) bb[j] = nb2[tx * 8 + j];
#pragma unroll
        for (int i = 0; i < 4; ++i) {
            int n = n0 + ty * 4 + i;
            if (n < N) {
#pragma unroll
                for (int j = 0; j < 8; ++j)
                    h[(size_t)n * HID + tx * 8 + j] = acc3[i][j] + bb[j];
            }
        }
    }
}

__global__ void k_proj(const float* __restrict__ h, const float* __restrict__ pw,
                       const float* __restrict__ pb, float* __restrict__ out, int N) {
    int idx = blockIdx.x * 256 + threadIdx.x;
    if (idx >= N * 3) return;
    int n = idx / 3, p = idx % 3;
    float s = pb[p];
    const float* hr = &h[(size_t)n * HID];
#pragma unroll 8
    for (int k = 0; k < HID; ++k) s += hr[k] * pw[k * 3 + p];
    out[idx] = s;
}

extern "C" void kernel_launch(void* const* d_in, const int* in_sizes, int n_in,
                              void* d_out, int out_size, void* d_ws, size_t ws_size,
                              hipStream_t stream)
{
    const float* h_in  = (const float*)d_in[0];
    const float* x_in  = (const float*)d_in[1];
    const float* v_in  = (const float*)d_in[2];
    const float* eattr = (const float*)d_in[3];
    const int*   edges = (const int*)d_in[4];
    const float* emb_w = (const float*)d_in[5];
    const float* emb_b = (const float*)d_in[6];
    const float* ew1   = (const float*)d_in[7];
    const float* eb1   = (const float*)d_in[8];
    const float* ew2   = (const float*)d_in[9];
    const float* eb2   = (const float*)d_in[10];
    const float* aw    = (const float*)d_in[11];
    const float* ab    = (const float*)d_in[12];
    const float* nw1   = (const float*)d_in[13];
    const float* nb1   = (const float*)d_in[14];
    const float* nw2   = (const float*)d_in[15];
    const float* nb2   = (const float*)d_in[16];
    const float* cw1   = (const float*)d_in[17];
    const float* cb1   = (const float*)d_in[18];
    const float* cw2   = (const float*)d_in[19];
    const float* vw1   = (const float*)d_in[20];
    const float* vb1   = (const float*)d_in[21];
    const float* vw2   = (const float*)d_in[22];
    const float* vb2   = (const float*)d_in[23];
    const float* pw    = (const float*)d_in[24];
    const float* pb    = (const float*)d_in[25];

    const int N = in_sizes[0] / 6;
    const int E = in_sizes[4] / 2;
    const int* rows = edges;
    const int* cols = edges + E;

    float* ws   = (float*)d_ws;
    float* hbuf = ws;  ws += (size_t)N * HID;
    float* aggh = ws;  ws += (size_t)N * HID;
    float* aggx = ws;  ws += (size_t)N * 3;
    float* xb   = ws;  ws += (size_t)N * 3;
    float* vb   = ws;  ws += (size_t)N * 3;
    float* cnt  = ws;  ws += N;
    unsigned short* us = (unsigned short*)ws;
    unsigned short* hhi = us;  us += (size_t)N * HID;
    unsigned short* hlo = us;  us += (size_t)N * HID;
    unsigned short* w1p = us;  us += 4 * 65536;
    unsigned short* w2p = us;  us += 4 * 32768;
    unsigned short* c1p = us;  us += 4 * 32768;
    float* outp = (float*)d_out;

    hipMemcpyAsync(xb, x_in, (size_t)N * 3 * sizeof(float), hipMemcpyDeviceToDevice, stream);
    hipMemcpyAsync(vb, v_in, (size_t)N * 3 * sizeof(float), hipMemcpyDeviceToDevice, stream);
    hipMemsetAsync(cnt, 0, N * sizeof(float), stream);
    k_count<<<(E + 255) / 256, 256, 0, stream>>>(rows, cnt, E);
    k_pack_w<<<(4 * 65536 + 255) / 256, 256, 0, stream>>>(ew1, ew2, cw1, w1p, w2p, c1p);
    k_embed<<<(N * HID + 255) / 256, 256, 0, stream>>>(h_in, emb_w, emb_b, hbuf, N);

    for (int l = 0; l < 4; ++l) {
        k_prep_h<<<(N * HID + 255) / 256, 256, 0, stream>>>(hbuf, hhi, hlo, N);
        hipMemsetAsync(aggh, 0, (size_t)N * HID * sizeof(float), stream);
        hipMemsetAsync(aggx, 0, (size_t)N * 3 * sizeof(float), stream);
        k_edge_mfma<<<(E + 63) / 64, 256, 0, stream>>>(
            hhi, hlo, xb, eattr, rows, cols,
            w1p + (size_t)l * 65536,
            ew1 + (size_t)l * 33152 + 256 * HID, eb1 + l * HID,
            w2p + (size_t)l * 32768, eb2 + l * HID,
            aw + l * HID, ab + l,
            c1p + (size_t)l * 32768, cb1 + l * HID, cw2 + l * HID,
            aggh, aggx, E);
        k_node<<<(N + 63) / 64, 256, 0, stream>>>(
            hbuf, aggh, aggx, cnt, xb, vb,
            vw1 + (size_t)l * HID * HID, vb1 + l * HID, vw2 + l * HID, vb2 + l,
            nw1 + (size_t)l * 2 * HID * HID, nb1 + l * HID,
            nw2 + (size_t)l * HID * HID, nb2 + l * HID, N);
    }
    k_proj<<<(N * 3 + 255) / 256, 256, 0, stream>>>(hbuf, pw, pb, outp, N);
    hipMemcpyAsync(outp + (size_t)N * 3, xb, (size_t)N * 3 * sizeof(float), hipMemcpyDeviceToDevice, stream);
    hipMemcpyAsync(outp + (size_t)N * 6, vb, (size_t)N * 3 * sizeof(float), hipMemcpyDeviceToDevice, stream);
}

// Round 4
// 1525.325 us; speedup vs baseline: 2.0456x; 1.0080x over previous
//
#include <hip/hip_runtime.h>
#include <math.h>

#define HID 128

typedef __attribute__((ext_vector_type(8))) short bf16x8;
typedef __attribute__((ext_vector_type(4))) float f32x4;

__device__ __forceinline__ float silu_f(float v) {
    return v / (1.0f + __expf(-v));
}
__device__ __forceinline__ float sigmoid_f(float v) {
    return 1.0f / (1.0f + __expf(-v));
}
__device__ __forceinline__ unsigned short bf16hi(float f) {
    return (unsigned short)(__float_as_uint(f) >> 16);
}
__device__ __forceinline__ float bf16tof(unsigned short u) {
    return __uint_as_float(((unsigned int)u) << 16);
}

__device__ __forceinline__ void stage16(const unsigned short* g, unsigned short* l) {
    __builtin_amdgcn_global_load_lds(
        (const __attribute__((address_space(1))) unsigned int*)g,
        (__attribute__((address_space(3))) unsigned int*)l, 16, 0, 0);
}
__device__ __forceinline__ void stage_chunk(const unsigned short* __restrict__ g,
                                            unsigned short* l, int t) {
    int wv = t >> 6, lane = t & 63;
    const unsigned short* gs = g + wv * 2048 + lane * 8;
    unsigned short* ls = l + wv * 2048 + lane * 8;
#pragma unroll
    for (int i = 0; i < 4; ++i)
        stage16(gs + i * 512, ls + i * 512);
}

// ---------- CSR / sort-by-row (rows static across layers; built once per call) ----------
__global__ void k_cnt(const int* __restrict__ rows, int* __restrict__ cnti, int E) {
    int i = blockIdx.x * 256 + threadIdx.x;
    if (i < E) atomicAdd(&cnti[rows[i]], 1);
}

// single-block exclusive scan over N counts -> base
__global__ void k_scan(const int* __restrict__ cnti, int* __restrict__ base, int N) {
    __shared__ int part[256];
    int t = threadIdx.x;
    int chunk = (N + 255) / 256;
    int lo = t * chunk, hi = lo + chunk < N ? lo + chunk : N;
    int s = 0;
    for (int i = lo; i < hi; ++i) s += cnti[i];
    part[t] = s;
    __syncthreads();
    for (int off = 1; off < 256; off <<= 1) {
        int v = (t >= off) ? part[t - off] : 0;
        __syncthreads();
        part[t] += v;
        __syncthreads();
    }
    int run = (t == 0) ? 0 : part[t - 1];
    for (int i = lo; i < hi; ++i) { base[i] = run; run += cnti[i]; }
}

__global__ void k_scatter(const int* __restrict__ rows, const int* __restrict__ cols,
                          const float* __restrict__ eattr,
                          const int* __restrict__ base, int* __restrict__ fill,
                          int* __restrict__ srow, int* __restrict__ scol,
                          float* __restrict__ sea, int E) {
    int e = blockIdx.x * 256 + threadIdx.x;
    if (e >= E) return;
    int r = rows[e];
    int pos = base[r] + atomicAdd(&fill[r], 1);
    srow[pos] = r;
    scol[pos] = cols[e];
    sea[pos * 2 + 0] = eattr[(size_t)e * 2 + 0];
    sea[pos * 2 + 1] = eattr[(size_t)e * 2 + 1];
}

__global__ void k_embed(const float* __restrict__ hin, const float* __restrict__ w,
                        const float* __restrict__ b, float* __restrict__ hout, int N) {
    int idx = blockIdx.x * 256 + threadIdx.x;
    if (idx >= N * HID) return;
    int n = idx >> 7, j = idx & 127;
    float s = b[j];
    const float* hr = &hin[n * 6];
#pragma unroll
    for (int k = 0; k < 6; ++k) s += hr[k] * w[k * HID + j];
    hout[idx] = s;
}

// pack weights: chunk (K=32) = [4 quads][hi 1024 | lo 1024 interleave][128 n][8 k]
__global__ void k_pack_w(const float* __restrict__ ew1, const float* __restrict__ ew2,
                         const float* __restrict__ cw1,
                         unsigned short* __restrict__ w1p, unsigned short* __restrict__ w2p,
                         unsigned short* __restrict__ c1p) {
    int idx = blockIdx.x * 256 + threadIdx.x;
    if (idx >= 4 * 65536) return;
    int l = idx >> 16, r = idx & 65535;
    const float* src;
    unsigned short* dst;
    int k, n;
    if (r < 32768) {
        k = r >> 7; n = r & 127;
        src = ew1 + (size_t)l * 33152 + k * 128 + n;
        dst = w1p + (size_t)l * 65536;
    } else if (r < 49152) {
        int rr = r - 32768; k = rr >> 7; n = rr & 127;
        src = ew2 + (size_t)l * 16384 + k * 128 + n;
        dst = w2p + (size_t)l * 32768;
    } else {
        int rr = r - 49152; k = rr >> 7; n = rr & 127;
        src = cw1 + (size_t)l * 16384 + k * 128 + n;
        dst = c1p + (size_t)l * 32768;
    }
    float f = *src;
    unsigned short hi = bf16hi(f);
    float rem = f - bf16tof(hi);
    int s = k >> 3;
    int b = s * 2048 + n * 8 + (k & 7);
    dst[b] = hi;
    dst[b + 1024] = bf16hi(rem);
}

__global__ void k_prep_h(const float* __restrict__ h, unsigned short* __restrict__ hhi,
                         unsigned short* __restrict__ hlo, int N) {
    int idx = blockIdx.x * 256 + threadIdx.x;
    if (idx >= N * HID) return;
    float f = h[idx];
    unsigned short hi = bf16hi(f);
    float rem = f - bf16tof(hi);
    hhi[idx] = hi; hlo[idx] = bf16hi(rem);
}

// MFMA edge kernel over SORTED edges: 64 edges/block (4 waves x 16), split bf16 x3,
// weights LDS-staged; aggregation via run-segmented in-register reduction.
__global__ __launch_bounds__(256, 2) void k_edge_mfma(
    const unsigned short* __restrict__ hhi, const unsigned short* __restrict__ hlo,
    const float* __restrict__ x,
    const int* __restrict__ srow, const int* __restrict__ scol,
    const float* __restrict__ sea,
    const unsigned short* __restrict__ w1p, const float* __restrict__ ew1_tail,
    const float* __restrict__ eb1,
    const unsigned short* __restrict__ w2p, const float* __restrict__ eb2,
    const float* __restrict__ aw, const float* __restrict__ ab,
    const unsigned short* __restrict__ c1p, const float* __restrict__ cb1,
    const float* __restrict__ cw2,
    float* __restrict__ aggh, float* __restrict__ aggx, int E)
{
    __shared__ __align__(16) unsigned short sW[2][8192];
    __shared__ __align__(16) unsigned short tHi[4][16][136];
    __shared__ __align__(16) unsigned short tLo[4][16][136];
    __shared__ float sCD[64][4];
    __shared__ float sEA[64][2];
    __shared__ int sRow[64], sCol[64];

    const int t = threadIdx.x;
    const int wv = t >> 6, lane = t & 63;
    const int quad = lane >> 4, ln = lane & 15;
    const int e0 = blockIdx.x * 64;

    if (t < 64) {
        int eg = e0 + t;
        int ec = eg < E ? eg : E - 1;
        int r = srow[ec], c = scol[ec];
        sRow[t] = r; sCol[t] = c;
        float dx = x[r * 3 + 0] - x[c * 3 + 0];
        float dy = x[r * 3 + 1] - x[c * 3 + 1];
        float dz = x[r * 3 + 2] - x[c * 3 + 2];
        sCD[t][0] = dx; sCD[t][1] = dy; sCD[t][2] = dz;
        sCD[t][3] = dx * dx + dy * dy + dz * dz;
        sEA[t][0] = sea[(size_t)ec * 2 + 0];
        sEA[t][1] = sea[(size_t)ec * 2 + 1];
    }
    stage_chunk(w1p, sW[0], t);
    __syncthreads();

    const int eL = wv * 16 + ln;
    const int rowN = sRow[eL], colN = sCol[eL];

    // ---- GEMM1 ----
    f32x4 acc[8];
#pragma unroll
    for (int i = 0; i < 8; ++i) acc[i] = (f32x4){0.f, 0.f, 0.f, 0.f};
#pragma unroll 1
    for (int kc = 0; kc < 8; ++kc) {
        const int p = kc & 1;
        if (kc < 7) stage_chunk(w1p + (kc + 1) * 8192, sW[p ^ 1], t);
        else        stage_chunk(w2p, sW[p ^ 1], t);
        int kg = kc * 32 + quad * 8;
        int node = (kg < 128) ? rowN : colN;
        int ko = kg & 127;
        bf16x8 ahi = *(const bf16x8*)(hhi + (size_t)node * HID + ko);
        bf16x8 alo = *(const bf16x8*)(hlo + (size_t)node * HID + ko);
        const unsigned short* bq = &sW[p][quad * 2048 + ln * 8];
#pragma unroll
        for (int t8 = 0; t8 < 8; ++t8) {
            bf16x8 bhi = *(const bf16x8*)(bq + t8 * 128);
            bf16x8 blo = *(const bf16x8*)(bq + 1024 + t8 * 128);
            acc[t8] = __builtin_amdgcn_mfma_f32_16x16x32_bf16(ahi, bhi, acc[t8], 0, 0, 0);
            acc[t8] = __builtin_amdgcn_mfma_f32_16x16x32_bf16(alo, bhi, acc[t8], 0, 0, 0);
            acc[t8] = __builtin_amdgcn_mfma_f32_16x16x32_bf16(ahi, blo, acc[t8], 0, 0, 0);
        }
        __syncthreads();
    }
    // tail + bias + silu -> act LDS
#pragma unroll
    for (int t8 = 0; t8 < 8; ++t8) {
        int n = t8 * 16 + ln;
        float w6 = ew1_tail[n], w7 = ew1_tail[128 + n], w8 = ew1_tail[256 + n];
        float bb = eb1[n];
#pragma unroll
        for (int r = 0; r < 4; ++r) {
            int m = wv * 16 + quad * 4 + r;
            float v = acc[t8][r] + sCD[m][3] * w6 + sEA[m][0] * w7 + sEA[m][1] * w8 + bb;
            v = silu_f(v);
            unsigned short hi = bf16hi(v);
            float rem = v - bf16tof(hi);
            tHi[wv][quad * 4 + r][n] = hi;
            tLo[wv][quad * 4 + r][n] = bf16hi(rem);
        }
    }
    __syncthreads();

    // ---- GEMM2 ----
    f32x4 acc2[8];
#pragma unroll
    for (int i = 0; i < 8; ++i) acc2[i] = (f32x4){0.f, 0.f, 0.f, 0.f};
#pragma unroll 1
    for (int kc = 0; kc < 4; ++kc) {
        const int p = kc & 1;
        if (kc < 3) stage_chunk(w2p + (kc + 1) * 8192, sW[p ^ 1], t);
        else        stage_chunk(c1p, sW[p ^ 1], t);
        bf16x8 ahi = *(const bf16x8*)&tHi[wv][ln][kc * 32 + quad * 8];
        bf16x8 alo = *(const bf16x8*)&tLo[wv][ln][kc * 32 + quad * 8];
        const unsigned short* bq = &sW[p][quad * 2048 + ln * 8];
#pragma unroll
        for (int t8 = 0; t8 < 8; ++t8) {
            bf16x8 bhi = *(const bf16x8*)(bq + t8 * 128);
            bf16x8 blo = *(const bf16x8*)(bq + 1024 + t8 * 128);
            acc2[t8] = __builtin_amdgcn_mfma_f32_16x16x32_bf16(ahi, bhi, acc2[t8], 0, 0, 0);
            acc2[t8] = __builtin_amdgcn_mfma_f32_16x16x32_bf16(alo, bhi, acc2[t8], 0, 0, 0);
            acc2[t8] = __builtin_amdgcn_mfma_f32_16x16x32_bf16(ahi, blo, acc2[t8], 0, 0, 0);
        }
        __syncthreads();
    }
    // silu + attention gate (acc2 becomes gated m)
    float pr[4] = {0.f, 0.f, 0.f, 0.f};
#pragma unroll
    for (int t8 = 0; t8 < 8; ++t8) {
        int n = t8 * 16 + ln;
        float bb = eb2[n], awn = aw[n];
#pragma unroll
        for (int r = 0; r < 4; ++r) {
            float v = silu_f(acc2[t8][r] + bb);
            acc2[t8][r] = v;
            pr[r] += v * awn;
        }
    }
    {
        float ab0 = ab[0];
#pragma unroll
        for (int r = 0; r < 4; ++r) {
            float p = pr[r];
            p += __shfl_xor(p, 1);
            p += __shfl_xor(p, 2);
            p += __shfl_xor(p, 4);
            p += __shfl_xor(p, 8);
            pr[r] = sigmoid_f(p + ab0);
        }
    }
#pragma unroll
    for (int t8 = 0; t8 < 8; ++t8) {
        int n = t8 * 16 + ln;
#pragma unroll
        for (int r = 0; r < 4; ++r) {
            float v = acc2[t8][r] * pr[r];
            acc2[t8][r] = v;
            unsigned short hi = bf16hi(v);
            float rem = v - bf16tof(hi);
            tHi[wv][quad * 4 + r][n] = hi;
            tLo[wv][quad * 4 + r][n] = bf16hi(rem);
        }
    }

    // ---- agg_h: run-segmented reduction over this wave's 16 sorted edges ----
    {
        int i = 0;
        while (i < 16) {
            int node = sRow[wv * 16 + i];
            int j = i + 1;
            while (j < 16 && sRow[wv * 16 + j] == node) ++j;
#pragma unroll
            for (int t8 = 0; t8 < 8; ++t8) {
                float s = 0.f;
#pragma unroll
                for (int r = 0; r < 4; ++r) {
                    int el = quad * 4 + r;
                    bool ok = (el >= i) && (el < j) && (e0 + wv * 16 + el < E);
                    s += ok ? acc2[t8][r] : 0.f;
                }
                s += __shfl_xor(s, 16);
                s += __shfl_xor(s, 32);
                if (quad == (t8 & 3))
                    atomicAdd(&aggh[(size_t)node * HID + t8 * 16 + ln], s);
            }
            i = j;
        }
    }
    __syncthreads();

    // ---- GEMM3 ----
    f32x4 acc3[8];
#pragma unroll
    for (int i = 0; i < 8; ++i) acc3[i] = (f32x4){0.f, 0.f, 0.f, 0.f};
#pragma unroll 1
    for (int kc = 0; kc < 4; ++kc) {
        const int p = kc & 1;
        if (kc < 3) stage_chunk(c1p + (kc + 1) * 8192, sW[p ^ 1], t);
        bf16x8 ahi = *(const bf16x8*)&tHi[wv][ln][kc * 32 + quad * 8];
        bf16x8 alo = *(const bf16x8*)&tLo[wv][ln][kc * 32 + quad * 8];
        const unsigned short* bq = &sW[p][quad * 2048 + ln * 8];
#pragma unroll
        for (int t8 = 0; t8 < 8; ++t8) {
            bf16x8 bhi = *(const bf16x8*)(bq + t8 * 128);
            bf16x8 blo = *(const bf16x8*)(bq + 1024 + t8 * 128);
            acc3[t8] = __builtin_amdgcn_mfma_f32_16x16x32_bf16(ahi, bhi, acc3[t8], 0, 0, 0);
            acc3[t8] = __builtin_amdgcn_mfma_f32_16x16x32_bf16(alo, bhi, acc3[t8], 0, 0, 0);
            acc3[t8] = __builtin_amdgcn_mfma_f32_16x16x32_bf16(ahi, blo, acc3[t8], 0, 0, 0);
        }
        if (kc < 3) __syncthreads();
    }
    {
        float pr3[4] = {0.f, 0.f, 0.f, 0.f};
#pragma unroll
        for (int t8 = 0; t8 < 8; ++t8) {
            int n = t8 * 16 + ln;
            float bb = cb1[n], cwn = cw2[n];
#pragma unroll
            for (int r = 0; r < 4; ++r) {
                float u = silu_f(acc3[t8][r] + bb);
                pr3[r] += u * cwn;
            }
        }
#pragma unroll
        for (int r = 0; r < 4; ++r) {
            float p = pr3[r];
            p += __shfl_xor(p, 1);
            p += __shfl_xor(p, 2);
            p += __shfl_xor(p, 4);
            p += __shfl_xor(p, 8);
            pr3[r] = p;   // wc for edge quad*4+r (per quad)
        }
        // ---- agg_x: run-segmented reduction ----
        int i = 0;
        while (i < 16) {
            int node = sRow[wv * 16 + i];
            int j = i + 1;
            while (j < 16 && sRow[wv * 16 + j] == node) ++j;
            float s = 0.f;
            if (ln < 3) {
#pragma unroll
                for (int r = 0; r < 4; ++r) {
                    int el = quad * 4 + r;
                    int m = wv * 16 + el;
                    bool ok = (el >= i) && (el < j) && (e0 + m < E);
                    s += ok ? sCD[m][ln] * pr3[r] : 0.f;
                }
            }
            s += __shfl_xor(s, 16);
            s += __shfl_xor(s, 32);
            if (quad == 0 && ln < 3)
                atomicAdd(&aggx[node * 3 + ln], s);
            i = j;
        }
    }
}

// 64 nodes per block, 256 threads (fp32)
__global__ __launch_bounds__(256, 2) void k_node(
    float* __restrict__ h, const float* __restrict__ aggh,
    const float* __restrict__ aggx, const int* __restrict__ cnti,
    float* __restrict__ x, float* __restrict__ vel,
    const float* __restrict__ vw1, const float* __restrict__ vb1,
    const float* __restrict__ vw2, const float* __restrict__ vb2,
    const float* __restrict__ nw1, const float* __restrict__ nb1,
    const float* __restrict__ nw2, const float* __restrict__ nb2,
    int N)
{
    __shared__ __align__(16) float BH[64][132];
    __shared__ __align__(16) float BG[64][132];
    const int t = threadIdx.x;
    const int tx = t & 15, ty = t >> 4;
    const int n0 = blockIdx.x * 64;

    for (int idx = t; idx < 64 * 32; idx += 256) {
        int r = idx >> 5, c4 = idx & 31;
        int n = n0 + r;
        float4 v0 = make_float4(0.f, 0.f, 0.f, 0.f), v1 = v0;
        if (n < N) {
            v0 = *(const float4*)&h[(size_t)n * HID + c4 * 4];
            v1 = *(const float4*)&aggh[(size_t)n * HID + c4 * 4];
        }
        *(float4*)&BH[r][c4 * 4] = v0;
        *(float4*)&BG[r][c4 * 4] = v1;
    }
    __syncthreads();

    {
        float acc[4][8];
#pragma unroll
        for (int i = 0; i < 4; ++i)
#pragma unroll
            for (int j = 0; j < 8; ++j) acc[i][j] = 0.f;
        const float* wp = &vw1[tx * 8];
#pragma unroll 4
        for (int k = 0; k < HID; ++k) {
            float4 w0 = *(const float4*)&wp[k * HID];
            float4 w1v = *(const float4*)&wp[k * HID + 4];
            float wv[8] = {w0.x, w0.y, w0.z, w0.w, w1v.x, w1v.y, w1v.z, w1v.w};
            float av[4];
#pragma unroll
            for (int i = 0; i < 4; ++i) av[i] = BH[ty * 4 + i][k];
#pragma unroll
            for (int i = 0; i < 4; ++i)
#pragma unroll
                for (int j = 0; j < 8; ++j) acc[i][j] += av[i] * wv[j];
        }
        float bb[8], w2v[8];
#pragma unroll
        for (int j = 0; j < 8; ++j) { bb[j] = vb1[tx * 8 + j]; w2v[j] = vw2[tx * 8 + j]; }
        float vb20 = vb2[0];
#pragma unroll
        for (int i = 0; i < 4; ++i) {
            float p = 0.f;
#pragma unroll
            for (int j = 0; j < 8; ++j) p += silu_f(acc[i][j] + bb[j]) * w2v[j];
            p += __shfl_xor(p, 1);
            p += __shfl_xor(p, 2);
            p += __shfl_xor(p, 4);
            p += __shfl_xor(p, 8);
            float vs = p + vb20;
            if (tx == 0) {
                int n = n0 + ty * 4 + i;
                if (n < N) {
                    float cc = fmaxf((float)cnti[n], 1.0f);
#pragma unroll
                    for (int d = 0; d < 3; ++d) {
                        float vn = vs * vel[n * 3 + d];
                        float xn = x[n * 3 + d] + aggx[n * 3 + d] / cc + vn;
                        vel[n * 3 + d] = vn;
                        x[n * 3 + d] = xn;
                    }
                }
            }
        }
    }

    float acc2[4][8];
#pragma unroll
    for (int i = 0; i < 4; ++i)
#pragma unroll
        for (int j = 0; j < 8; ++j) acc2[i][j] = 0.f;
    {
        const float* wp = &nw1[tx * 8];
#pragma unroll 4
        for (int k = 0; k < HID; ++k) {
            float4 w0 = *(const float4*)&wp[k * HID];
            float4 w1v = *(const float4*)&wp[k * HID + 4];
            float wv[8] = {w0.x, w0.y, w0.z, w0.w, w1v.x, w1v.y, w1v.z, w1v.w};
            float av[4];
#pragma unroll
            for (int i = 0; i < 4; ++i) av[i] = BH[ty * 4 + i][k];
#pragma unroll
            for (int i = 0; i < 4; ++i)
#pragma unroll
                for (int j = 0; j < 8; ++j) acc2[i][j] += av[i] * wv[j];
        }
        const float* wp2 = &nw1[128 * HID + tx * 8];
#pragma unroll 4
        for (int k = 0; k < HID; ++k) {
            float4 w0 = *(const float4*)&wp2[k * HID];
            float4 w1v = *(const float4*)&wp2[k * HID + 4];
            float wv[8] = {w0.x, w0.y, w0.z, w0.w, w1v.x, w1v.y, w1v.z, w1v.w};
            float av[4];
#pragma unroll
            for (int i = 0; i < 4; ++i) av[i] = BG[ty * 4 + i][k];
#pragma unroll
            for (int i = 0; i < 4; ++i)
#pragma unroll
                for (int j = 0; j < 8; ++j) acc2[i][j] += av[i] * wv[j];
        }
    }
    __syncthreads();
    {
        float bb[8];
#pragma unroll
        for (int j = 0; j < 8; ++j) bb[j] = nb1[tx * 8 + j];
#pragma unroll
        for (int i = 0; i < 4; ++i)
#pragma unroll
            for (int j = 0; j < 8; ++j)
                BH[ty * 4 + i][tx * 8 + j] = silu_f(acc2[i][j] + bb[j]);
    }
    __syncthreads();
    float acc3[4][8];
#pragma unroll
    for (int i = 0; i < 4; ++i)
#pragma unroll
        for (int j = 0; j < 8; ++j) acc3[i][j] = 0.f;
    {
        const float* wp = &nw2[tx * 8];
#pragma unroll 4
        for (int k = 0; k < HID; ++k) {
            float4 w0 = *(const float4*)&wp[k * HID];
            float4 w1v = *(const float4*)&wp[k * HID + 4];
            float wv[8] = {w0.x, w0.y, w0.z, w0.w, w1v.x, w1v.y, w1v.z, w1v.w};
            float av[4];
#pragma unroll
            for (int i = 0; i < 4; ++i) av[i] = BH[ty * 4 + i][k];
#pragma unroll
            for (int i = 0; i < 4; ++i)
#pragma unroll
                for (int j = 0; j < 8; ++j) acc3[i][j] += av[i] * wv[j];
        }
    }
    {
        float bb[8];
#pragma unroll
        for (int j = 0; j < 8; ++j) bb[j] = nb2[tx * 8 + j];
#pragma unroll
        for (int i = 0; i < 4; ++i) {
            int n = n0 + ty * 4 + i;
            if (n < N) {
#pragma unroll
                for (int j = 0; j < 8; ++j)
                    h[(size_t)n * HID + tx * 8 + j] = acc3[i][j] + bb[j];
            }
        }
    }
}

__global__ void k_proj(const float* __restrict__ h, const float* __restrict__ pw,
                       const float* __restrict__ pb, float* __restrict__ out, int N) {
    int idx = blockIdx.x * 256 + threadIdx.x;
    if (idx >= N * 3) return;
    int n = idx / 3, p = idx % 3;
    float s = pb[p];
    const float* hr = &h[(size_t)n * HID];
#pragma unroll 8
    for (int k = 0; k < HID; ++k) s += hr[k] * pw[k * 3 + p];
    out[idx] = s;
}

extern "C" void kernel_launch(void* const* d_in, const int* in_sizes, int n_in,
                              void* d_out, int out_size, void* d_ws, size_t ws_size,
                              hipStream_t stream)
{
    const float* h_in  = (const float*)d_in[0];
    const float* x_in  = (const float*)d_in[1];
    const float* v_in  = (const float*)d_in[2];
    const float* eattr = (const float*)d_in[3];
    const int*   edges = (const int*)d_in[4];
    const float* emb_w = (const float*)d_in[5];
    const float* emb_b = (const float*)d_in[6];
    const float* ew1   = (const float*)d_in[7];
    const float* eb1   = (const float*)d_in[8];
    const float* ew2   = (const float*)d_in[9];
    const float* eb2   = (const float*)d_in[10];
    const float* aw    = (const float*)d_in[11];
    const float* ab    = (const float*)d_in[12];
    const float* nw1   = (const float*)d_in[13];
    const float* nb1   = (const float*)d_in[14];
    const float* nw2   = (const float*)d_in[15];
    const float* nb2   = (const float*)d_in[16];
    const float* cw1   = (const float*)d_in[17];
    const float* cb1   = (const float*)d_in[18];
    const float* cw2   = (const float*)d_in[19];
    const float* vw1   = (const float*)d_in[20];
    const float* vb1   = (const float*)d_in[21];
    const float* vw2   = (const float*)d_in[22];
    const float* vb2   = (const float*)d_in[23];
    const float* pw    = (const float*)d_in[24];
    const float* pb    = (const float*)d_in[25];

    const int N = in_sizes[0] / 6;
    const int E = in_sizes[4] / 2;
    const int* rows = edges;
    const int* cols = edges + E;

    float* ws   = (float*)d_ws;
    float* hbuf = ws;  ws += (size_t)N * HID;
    float* aggh = ws;  ws += (size_t)N * HID;
    float* aggx = ws;  ws += (size_t)N * 3;
    float* xb   = ws;  ws += (size_t)N * 3;
    float* vb   = ws;  ws += (size_t)N * 3;
    float* sea  = ws;  ws += (size_t)E * 2;
    int* wi = (int*)ws;
    int* cnti = wi;  wi += N;
    int* basei = wi; wi += N;
    int* fill = wi;  wi += N;
    int* srow = wi;  wi += E;
    int* scol = wi;  wi += E;
    unsigned short* us = (unsigned short*)wi;
    unsigned short* hhi = us;  us += (size_t)N * HID;
    unsigned short* hlo = us;  us += (size_t)N * HID;
    unsigned short* w1p = us;  us += 4 * 65536;
    unsigned short* w2p = us;  us += 4 * 32768;
    unsigned short* c1p = us;  us += 4 * 32768;
    float* outp = (float*)d_out;

    hipMemcpyAsync(xb, x_in, (size_t)N * 3 * sizeof(float), hipMemcpyDeviceToDevice, stream);
    hipMemcpyAsync(vb, v_in, (size_t)N * 3 * sizeof(float), hipMemcpyDeviceToDevice, stream);
    hipMemsetAsync(cnti, 0, 2 * N * sizeof(int), stream);  // cnti is NOT adjacent to fill; zero separately
    hipMemsetAsync(fill, 0, N * sizeof(int), stream);
    k_cnt<<<(E + 255) / 256, 256, 0, stream>>>(rows, cnti, E);
    k_scan<<<1, 256, 0, stream>>>(cnti, basei, N);
    k_scatter<<<(E + 255) / 256, 256, 0, stream>>>(rows, cols, eattr, basei, fill,
                                                   srow, scol, sea, E);
    k_pack_w<<<(4 * 65536 + 255) / 256, 256, 0, stream>>>(ew1, ew2, cw1, w1p, w2p, c1p);
    k_embed<<<(N * HID + 255) / 256, 256, 0, stream>>>(h_in, emb_w, emb_b, hbuf, N);

    for (int l = 0; l < 4; ++l) {
        k_prep_h<<<(N * HID + 255) / 256, 256, 0, stream>>>(hbuf, hhi, hlo, N);
        hipMemsetAsync(aggh, 0, (size_t)N * HID * sizeof(float), stream);
        hipMemsetAsync(aggx, 0, (size_t)N * 3 * sizeof(float), stream);
        k_edge_mfma<<<(E + 63) / 64, 256, 0, stream>>>(
            hhi, hlo, xb, srow, scol, sea,
            w1p + (size_t)l * 65536,
            ew1 + (size_t)l * 33152 + 256 * HID, eb1 + l * HID,
            w2p + (size_t)l * 32768, eb2 + l * HID,
            aw + l * HID, ab + l,
            c1p + (size_t)l * 32768, cb1 + l * HID, cw2 + l * HID,
            aggh, aggx, E);
        k_node<<<(N + 63) / 64, 256, 0, stream>>>(
            hbuf, aggh, aggx, cnti, xb, vb,
            vw1 + (size_t)l * HID * HID, vb1 + l * HID, vw2 + l * HID, vb2 + l,
            nw1 + (size_t)l * 2 * HID * HID, nb1 + l * HID,
            nw2 + (size_t)l * HID * HID, nb2 + l * HID, N);
    }
    k_proj<<<(N * 3 + 255) / 256, 256, 0, stream>>>(hbuf, pw, pb, outp, N);
    hipMemcpyAsync(outp + (size_t)N * 3, xb, (size_t)N * 3 * sizeof(float), hipMemcpyDeviceToDevice, stream);
    hipMemcpyAsync(outp + (size_t)N * 6, vb, (size_t)N * 3 * sizeof(float), hipMemcpyDeviceToDevice, stream);
}